// Round 9
// baseline (458.817 us; speedup 1.0000x reference)
//
#include <hip/hip_runtime.h>
#include <cstdint>
#include <cstddef>

// ClusterProtoNetwork: pre-converted bf16 operands -> ONE merged GEMM launch
// (blocks [0,512): sup BM=64 3-product; [512,1024): qry BM=128 1-product) ->
// per-class Gram kmeans (incremental fp32) -> protos (2-stage) -> cdist.
// Fallback in-loop-convert GEMM if workspace too small.

typedef __attribute__((ext_vector_type(4))) float f32x4;
typedef __attribute__((ext_vector_type(8))) short s16x8;
typedef __attribute__((ext_vector_type(4))) short s16x4;
typedef __attribute__((ext_vector_type(8))) __bf16 bf16x8;

__device__ __forceinline__ unsigned short f2bf(float f) {
  unsigned u = __float_as_uint(f);
  return (unsigned short)((u + 0x7FFFu + ((u >> 16) & 1u)) >> 16);  // RTNE
}
__device__ __forceinline__ float bf2f(unsigned short h) {
  return __uint_as_float(((unsigned)h) << 16);
}

typedef const __attribute__((address_space(1))) void GV;
typedef __attribute__((address_space(3))) void LV;
__device__ __forceinline__ void gload_lds16(const void* g, void* l) {
  __builtin_amdgcn_global_load_lds((GV*)g, (LV*)l, 16, 0, 0);
}
__device__ __forceinline__ f32x4 mfma16(bf16x8 a, bf16x8 b, f32x4 c) {
  return __builtin_amdgcn_mfma_f32_16x16x32_bf16(a, b, c, 0, 0, 0);
}
__device__ __forceinline__ float wave_sum(float v) {
#pragma unroll
  for (int st = 1; st < 64; st <<= 1) v += __shfl_xor(v, st);
  return v;
}

// ---------------- Threefry-2x32 (JAX-exact, 20 rounds) ----------------
__device__ __forceinline__ void tf2x32(unsigned k0, unsigned k1, unsigned x0,
                                       unsigned x1, unsigned& y0, unsigned& y1) {
  unsigned ks0 = k0, ks1 = k1, ks2 = k0 ^ k1 ^ 0x1BD11BDAu;
  x0 += ks0; x1 += ks1;
  const int rA[4] = {13, 15, 26, 6};
  const int rB[4] = {17, 29, 16, 24};
#define ROTL(v, d) (((v) << (d)) | ((v) >> (32 - (d))))
#define RG(R)                                     \
  _Pragma("unroll") for (int i = 0; i < 4; i++) { \
    x0 += x1; x1 = ROTL(x1, R[i]); x1 ^= x0;      \
  }
  RG(rA); x0 += ks1; x1 += ks2 + 1u;
  RG(rB); x0 += ks2; x1 += ks0 + 2u;
  RG(rA); x0 += ks0; x1 += ks1 + 3u;
  RG(rB); x0 += ks1; x1 += ks2 + 4u;
  RG(rA); x0 += ks2; x1 += ks0 + 5u;
#undef RG
#undef ROTL
  y0 = x0; y1 = x1;
}

// ---- 1. merged prep: W -> WhiT/WloT (transposed split); sup/qry -> bf16 ---
__global__ __launch_bounds__(256) void prep_k(
    const float* __restrict__ W, const float* __restrict__ sup,
    const float* __restrict__ qry, short* __restrict__ WhiT,
    short* __restrict__ WloT, short* __restrict__ Shi,
    short* __restrict__ Slo, short* __restrict__ Qhi) {
  __shared__ float tile[64][65];
  int t = threadIdx.x;
  if (blockIdx.x < 1024) {  // prepw: 64 k-tiles x 16 n-tiles of 64x64
    int bk = blockIdx.x & 63, bn = blockIdx.x >> 6;
#pragma unroll
    for (int i = 0; i < 4; i++) {
      int row = i * 16 + (t >> 4);
      int col = (t & 15) * 4;
      f32x4 v =
          *(const f32x4*)(W + (size_t)(bk * 64 + row) * 1024 + bn * 64 + col);
      tile[row][col + 0] = v[0]; tile[row][col + 1] = v[1];
      tile[row][col + 2] = v[2]; tile[row][col + 3] = v[3];
    }
    __syncthreads();
#pragma unroll
    for (int i = 0; i < 4; i++) {
      int nrow = i * 16 + (t >> 4);
      int kcol = (t & 15) * 4;
      s16x4 hv, lv;
#pragma unroll
      for (int e = 0; e < 4; e++) {
        float v = tile[kcol + e][nrow];
        unsigned short h = f2bf(v);
        hv[e] = (short)h;
        lv[e] = (short)f2bf(v - bf2f(h));
      }
      size_t off = (size_t)(bn * 64 + nrow) * 4096 + bk * 64 + kcol;
      *(s16x4*)(WhiT + off) = hv;
      *(s16x4*)(WloT + off) = lv;
    }
  } else {  // prepa: grid-stride over 6M 8-elem chunks
    const size_t sup_n8 = (size_t)4096 * 4096 / 8;  // 2M
    const size_t tot_n8 = sup_n8 + (size_t)8192 * 4096 / 8;  // 6M
    size_t stride = (size_t)(gridDim.x - 1024) * 256;
    for (size_t gid = (size_t)(blockIdx.x - 1024) * 256 + t; gid < tot_n8;
         gid += stride) {
      if (gid < sup_n8) {
        const float* src = sup + gid * 8;
        f32x4 v0 = *(const f32x4*)src, v1 = *(const f32x4*)(src + 4);
        s16x8 h, l;
#pragma unroll
        for (int e = 0; e < 4; e++) {
          unsigned short hh = f2bf(v0[e]);
          h[e] = (short)hh; l[e] = (short)f2bf(v0[e] - bf2f(hh));
        }
#pragma unroll
        for (int e = 0; e < 4; e++) {
          unsigned short hh = f2bf(v1[e]);
          h[4 + e] = (short)hh; l[4 + e] = (short)f2bf(v1[e] - bf2f(hh));
        }
        *(s16x8*)(Shi + gid * 8) = h;
        *(s16x8*)(Slo + gid * 8) = l;
      } else {
        size_t q = gid - sup_n8;
        const float* src = qry + q * 8;
        f32x4 v0 = *(const f32x4*)src, v1 = *(const f32x4*)(src + 4);
        s16x8 h;
#pragma unroll
        for (int e = 0; e < 4; e++) h[e] = (short)f2bf(v0[e]);
#pragma unroll
        for (int e = 0; e < 4; e++) h[4 + e] = (short)f2bf(v1[e]);
        *(s16x8*)(Qhi + q * 8) = h;
      }
    }
  }
}

// ---- 2. merged GEMM launch: [0,512) sup (BM=64, 3-product, 48 KiB LDS);
//         [512,1024) qry (BM=128, 1-product, uses 32 KiB of the 48).
//     One launch -> qry blocks backfill sup's tail round (no kernel gap).
__global__ __launch_bounds__(256) void gemm_both_k(
    const short* __restrict__ Shi, const short* __restrict__ Slo,
    const short* __restrict__ Qhi, const short* __restrict__ WhiT,
    const short* __restrict__ WloT, const float* __restrict__ bias,
    float* __restrict__ emb) {
  __shared__ short lds[24576];  // 48 KiB
  const int t = threadIdx.x, lane = t & 63, w = t >> 6;
  const int wr = w >> 1, wc = w & 1;
  const int fr = lane & 15, kg = lane >> 4;
  const int ls = lane >> 3, lc = lane & 7;
  const int cchv = (lc ^ ls) * 8;

  if (blockIdx.x < 512) {
    // ---------------- support path: BM=64, 3-product ----------------
    short* Ah = lds;          // [64][64]
    short* Al = lds + 4096;   // [64][64]
    short* Bh = lds + 8192;   // [128][64]
    short* Bl = lds + 16384;  // [128][64]
    const int bid = blockIdx.x;
    const int bm = bid & 63, bn = bid >> 6;  // siblings +64 -> same XCD
    const short* Ag = Shi + (size_t)bm * 64 * 4096;
    const short* Alg = Slo + (size_t)bm * 64 * 4096;
    f32x4 acc[2][4] = {};

    for (int kt = 0; kt < 64; ++kt) {
      const int k0 = kt * 64;
      __syncthreads();
#pragma unroll
      for (int j = 0; j < 2; j++) {
        int rowl = w * 16 + j * 8 + ls;
        size_t aoff = (size_t)rowl * 4096 + k0 + cchv;
        int ldst = (w * 16 + j * 8) * 64;
        gload_lds16(Ag + aoff, Ah + ldst);
        gload_lds16(Alg + aoff, Al + ldst);
      }
#pragma unroll
      for (int j = 0; j < 4; j++) {
        int rowl = w * 32 + j * 8 + ls;
        size_t boff = (size_t)(bn * 128 + rowl) * 4096 + k0 + cchv;
        int ldst = (w * 32 + j * 8) * 64;
        gload_lds16(WhiT + boff, Bh + ldst);
        gload_lds16(WloT + boff, Bl + ldst);
      }
      __syncthreads();
#pragma unroll
      for (int ks = 0; ks < 2; ++ks) {
        const int cx = ((ks * 4 + kg) ^ (fr & 7)) * 8;
        bf16x8 ahf[2], alf[2], bhf[4], blf[4];
#pragma unroll
        for (int mi = 0; mi < 2; mi++) {
          int arow = wr * 32 + mi * 16 + fr;
          ahf[mi] =
              __builtin_bit_cast(bf16x8, *(const s16x8*)(Ah + arow * 64 + cx));
          alf[mi] =
              __builtin_bit_cast(bf16x8, *(const s16x8*)(Al + arow * 64 + cx));
        }
#pragma unroll
        for (int ni = 0; ni < 4; ni++) {
          int brow = wc * 64 + ni * 16 + fr;
          bhf[ni] =
              __builtin_bit_cast(bf16x8, *(const s16x8*)(Bh + brow * 64 + cx));
          blf[ni] =
              __builtin_bit_cast(bf16x8, *(const s16x8*)(Bl + brow * 64 + cx));
        }
#pragma unroll
        for (int mi = 0; mi < 2; mi++)
#pragma unroll
          for (int ni = 0; ni < 4; ni++) {
            acc[mi][ni] = mfma16(ahf[mi], bhf[ni], acc[mi][ni]);
            acc[mi][ni] = mfma16(ahf[mi], blf[ni], acc[mi][ni]);
            acc[mi][ni] = mfma16(alf[mi], bhf[ni], acc[mi][ni]);
          }
      }
    }
#pragma unroll
    for (int ni = 0; ni < 4; ni++) {
      int gc = bn * 128 + wc * 64 + ni * 16 + fr;
      float bv = bias[gc];
#pragma unroll
      for (int mi = 0; mi < 2; mi++) {
        int gr = bm * 64 + wr * 32 + mi * 16 + kg * 4;
#pragma unroll
        for (int r = 0; r < 4; r++)
          emb[(size_t)(gr + r) * 1024 + gc] = acc[mi][ni][r] + bv;
      }
    }
  } else {
    // ---------------- query path: BM=128, 1-product ----------------
    short* Ah = lds;          // [128][64]
    short* Bh = lds + 8192;   // [128][64]
    const int bid = blockIdx.x - 512;
    const int bm = bid & 63, bn = bid >> 6;  // siblings +64 -> same XCD
    const short* Ag = Qhi + (size_t)bm * 128 * 4096;
    f32x4 acc[4][4] = {};

    for (int kt = 0; kt < 64; ++kt) {
      const int k0 = kt * 64;
      __syncthreads();
#pragma unroll
      for (int j = 0; j < 4; j++) {
        int rowl = w * 32 + j * 8 + ls;
        size_t aoff = (size_t)rowl * 4096 + k0 + cchv;
        size_t boff = (size_t)(bn * 128 + rowl) * 4096 + k0 + cchv;
        int ldst = (w * 32 + j * 8) * 64;
        gload_lds16(Ag + aoff, Ah + ldst);
        gload_lds16(WhiT + boff, Bh + ldst);
      }
      __syncthreads();
#pragma unroll
      for (int ks = 0; ks < 2; ++ks) {
        const int cx = ((ks * 4 + kg) ^ (fr & 7)) * 8;
        bf16x8 ahf[4], bhf[4];
#pragma unroll
        for (int mi = 0; mi < 4; mi++) {
          int arow = wr * 64 + mi * 16 + fr;
          ahf[mi] =
              __builtin_bit_cast(bf16x8, *(const s16x8*)(Ah + arow * 64 + cx));
        }
#pragma unroll
        for (int ni = 0; ni < 4; ni++) {
          int brow = wc * 64 + ni * 16 + fr;
          bhf[ni] =
              __builtin_bit_cast(bf16x8, *(const s16x8*)(Bh + brow * 64 + cx));
        }
#pragma unroll
        for (int mi = 0; mi < 4; mi++)
#pragma unroll
          for (int ni = 0; ni < 4; ni++)
            acc[mi][ni] = mfma16(ahf[mi], bhf[ni], acc[mi][ni]);
      }
    }
#pragma unroll
    for (int ni = 0; ni < 4; ni++) {
      int gc = bn * 128 + wc * 64 + ni * 16 + fr;
      float bv = bias[gc];
#pragma unroll
      for (int mi = 0; mi < 4; mi++) {
        int gr = 4096 + bm * 128 + wr * 64 + mi * 16 + kg * 4;
#pragma unroll
        for (int r = 0; r < 4; r++)
          emb[(size_t)(gr + r) * 1024 + gc] = acc[mi][ni][r] + bv;
      }
    }
  }
}

// ---- 2'. fallback GEMM (in-loop convert; used when ws too small) ----------
__global__ __launch_bounds__(256) void gemm_all_k(
    const float* __restrict__ sup, const float* __restrict__ qry,
    const short* __restrict__ WhiT, const short* __restrict__ WloT,
    const float* __restrict__ bias, float* __restrict__ emb) {
  __shared__ short lds[4 * 128 * 64];
  short* Ah = lds;
  short* Al = lds + 8192;
  short* Bh = lds + 16384;
  short* Bl = lds + 24576;
  const int bid = blockIdx.x;
  const int bm = bid % 96, bn = bid / 96;
  const bool is_sup = bm < 32;
  const int t = threadIdx.x, lane = t & 63, w = t >> 6;
  const int wr = w >> 1, wc = w & 1;
  const int fr = lane & 15, kg = lane >> 4;
  const float* Abase = is_sup ? (sup + (size_t)bm * 128 * 4096)
                              : (qry + (size_t)(bm - 32) * 128 * 4096);
  f32x4 acc[4][4] = {};
  const int ls = lane >> 3, lc = lane & 7;

  for (int kt = 0; kt < 64; ++kt) {
    const int k0 = kt * 64;
    __syncthreads();
#pragma unroll
    for (int i = 0; i < 4; i++) {
      int row = i * 32 + w * 8 + ls;
      const float* src = Abase + (size_t)row * 4096 + k0 + lc * 8;
      f32x4 v0 = *(const f32x4*)src;
      f32x4 v1 = *(const f32x4*)(src + 4);
      s16x8 hs;
#pragma unroll
      for (int e = 0; e < 4; e++) hs[e] = (short)f2bf(v0[e]);
#pragma unroll
      for (int e = 0; e < 4; e++) hs[4 + e] = (short)f2bf(v1[e]);
      int chunk = lc ^ (row & 7);
      *(s16x8*)(Ah + row * 64 + chunk * 8) = hs;
      if (is_sup) {
        s16x8 lsv;
#pragma unroll
        for (int e = 0; e < 4; e++)
          lsv[e] = (short)f2bf(v0[e] - bf2f((unsigned short)hs[e]));
#pragma unroll
        for (int e = 0; e < 4; e++)
          lsv[4 + e] = (short)f2bf(v1[e] - bf2f((unsigned short)hs[4 + e]));
        *(s16x8*)(Al + row * 64 + chunk * 8) = lsv;
      }
    }
#pragma unroll
    for (int j = 0; j < 4; j++) {
      int rowl = w * 32 + j * 8 + ls;
      int cch = (lc ^ (ls & 7)) * 8;
      size_t goff = (size_t)(bn * 128 + rowl) * 4096 + k0 + cch;
      gload_lds16(WhiT + goff, Bh + (w * 32 + j * 8) * 64);
      if (is_sup) gload_lds16(WloT + goff, Bl + (w * 32 + j * 8) * 64);
    }
    __syncthreads();
#pragma unroll
    for (int ks = 0; ks < 2; ++ks) {
      const int cx = ((ks * 4 + kg) ^ (fr & 7)) * 8;
      bf16x8 ahf[4], bhf[4];
#pragma unroll
      for (int mi = 0; mi < 4; mi++) {
        int arow = wr * 64 + mi * 16 + fr;
        ahf[mi] = __builtin_bit_cast(bf16x8, *(const s16x8*)(Ah + arow * 64 + cx));
      }
#pragma unroll
      for (int ni = 0; ni < 4; ni++) {
        int brow = wc * 64 + ni * 16 + fr;
        bhf[ni] = __builtin_bit_cast(bf16x8, *(const s16x8*)(Bh + brow * 64 + cx));
      }
      if (is_sup) {
        bf16x8 alf[4], blf[4];
#pragma unroll
        for (int mi = 0; mi < 4; mi++) {
          int arow = wr * 64 + mi * 16 + fr;
          alf[mi] =
              __builtin_bit_cast(bf16x8, *(const s16x8*)(Al + arow * 64 + cx));
        }
#pragma unroll
        for (int ni = 0; ni < 4; ni++) {
          int brow = wc * 64 + ni * 16 + fr;
          blf[ni] =
              __builtin_bit_cast(bf16x8, *(const s16x8*)(Bl + brow * 64 + cx));
        }
#pragma unroll
        for (int mi = 0; mi < 4; mi++)
#pragma unroll
          for (int ni = 0; ni < 4; ni++) {
            acc[mi][ni] = mfma16(ahf[mi], bhf[ni], acc[mi][ni]);
            acc[mi][ni] = mfma16(ahf[mi], blf[ni], acc[mi][ni]);
            acc[mi][ni] = mfma16(alf[mi], bhf[ni], acc[mi][ni]);
          }
      } else {
#pragma unroll
        for (int mi = 0; mi < 4; mi++)
#pragma unroll
          for (int ni = 0; ni < 4; ni++)
            acc[mi][ni] = mfma16(ahf[mi], bhf[ni], acc[mi][ni]);
      }
    }
  }
#pragma unroll
  for (int ni = 0; ni < 4; ni++) {
    int gc = bn * 128 + wc * 64 + ni * 16 + fr;
    float bv = bias[gc];
#pragma unroll
    for (int mi = 0; mi < 4; mi++) {
      int gr = bm * 128 + wr * 64 + mi * 16 + kg * 4;
#pragma unroll
      for (int r = 0; r < 4; r++)
        emb[(size_t)(gr + r) * 1024 + gc] = acc[mi][ni][r] + bv;
    }
  }
}

// ---------------- 3. per-class Gram G = S S^T (fp32 vector) ----------------
__global__ __launch_bounds__(256) void gram_k(const float* __restrict__ emb,
                                              float* __restrict__ G) {
  int c = blockIdx.x >> 4, tl = blockIdx.x & 15, ti = tl >> 2, tj = tl & 3;
  __shared__ float As[64][36];
  __shared__ float Bs[32][68];
  int t = threadIdx.x, ty = t >> 4, tx = t & 15;
  const float* base = emb + (size_t)c * 256 * 1024;
  float acc[4][4] = {};
  for (int k0 = 0; k0 < 1024; k0 += 32) {
    __syncthreads();
    {
      int r = t >> 2, seg = t & 3;
      const float* pa = base + (size_t)(ti * 64 + r) * 1024 + k0 + seg * 8;
      f32x4 va0 = *(const f32x4*)pa, va1 = *(const f32x4*)(pa + 4);
      *(f32x4*)(&As[r][seg * 8]) = va0;
      *(f32x4*)(&As[r][seg * 8 + 4]) = va1;
      const float* pb = base + (size_t)(tj * 64 + r) * 1024 + k0 + seg * 8;
      f32x4 vb0 = *(const f32x4*)pb, vb1 = *(const f32x4*)(pb + 4);
#pragma unroll
      for (int e = 0; e < 4; e++) Bs[seg * 8 + e][r] = vb0[e];
#pragma unroll
      for (int e = 0; e < 4; e++) Bs[seg * 8 + 4 + e][r] = vb1[e];
    }
    __syncthreads();
#pragma unroll 4
    for (int kk = 0; kk < 32; kk++) {
      float a0 = As[ty * 4 + 0][kk], a1 = As[ty * 4 + 1][kk];
      float a2 = As[ty * 4 + 2][kk], a3 = As[ty * 4 + 3][kk];
      f32x4 bv = *(const f32x4*)(&Bs[kk][tx * 4]);
#pragma unroll
      for (int jdx = 0; jdx < 4; jdx++) {
        acc[0][jdx] = fmaf(a0, bv[jdx], acc[0][jdx]);
        acc[1][jdx] = fmaf(a1, bv[jdx], acc[1][jdx]);
        acc[2][jdx] = fmaf(a2, bv[jdx], acc[2][jdx]);
        acc[3][jdx] = fmaf(a3, bv[jdx], acc[3][jdx]);
      }
    }
  }
#pragma unroll
  for (int i = 0; i < 4; i++) {
    int gr = ti * 64 + ty * 4 + i;
#pragma unroll
    for (int j = 0; j < 4; j++)
      G[(size_t)c * 65536 + (size_t)gr * 256 + tj * 64 + tx * 4 + j] = acc[i][j];
  }
}

// ---------------- 3b. overwrite G diagonal with f64-exact |x_i|^2 ----------
__global__ __launch_bounds__(256) void diag_k(const float* __restrict__ emb,
                                              float* __restrict__ G) {
  int r = blockIdx.x * 4 + (threadIdx.x >> 6);  // support row 0..4095
  int lane = threadIdx.x & 63;
  const float* x = emb + (size_t)r * 1024;
  double acc = 0.0;
#pragma unroll
  for (int ch = 0; ch < 16; ch++) {
    float v = x[ch * 64 + lane];
    acc = fma((double)v, (double)v, acc);
  }
#pragma unroll
  for (int st = 1; st < 64; st <<= 1) acc += __shfl_xor(acc, st);
  if (lane == 0) {
    int c = r >> 8, i = r & 255;
    G[(size_t)c * 65536 + (size_t)i * 256 + i] = (float)acc;
  }
}

// -------- 4. per-class kmeans, incremental fp32 S updates (100 iters) ------
__global__ __launch_bounds__(256) void kmeans2_k(const float* __restrict__ G,
                                                 float* __restrict__ wts) {
  const int c = blockIdx.x;
  const int t = threadIdx.x, lane = t & 63, w = t >> 6;
  __shared__ unsigned dmL[256], nmL[256];
  __shared__ unsigned short chg[256];
  __shared__ unsigned sk[256];
  __shared__ unsigned idx5[5];
  __shared__ float Tpart[4][5], Tu[5], C2[5], Minv[5];
  __shared__ int Hp[4][5], Ncnt[5], cntW[4];

  // --- RNG (threefry PARTITIONABLE mode, JAX >= 0.4.36 default)
  {
    unsigned o0, o1, s0k, s1k, y0, y1;
    tf2x32(0u, 42u, 0u, (unsigned)c, o0, o1);
    tf2x32(o0, o1, 0u, 1u, s0k, s1k);
    tf2x32(s0k, s1k, 0u, (unsigned)t, y0, y1);
    sk[t] = y0 ^ y1;
  }
  __syncthreads();
  {
    unsigned kt_ = sk[t];
    int rank = 0;
    for (int j = 0; j < 256; j++) {
      unsigned kj = sk[j];
      rank += (kj < kt_ || (kj == kt_ && j < t)) ? 1 : 0;
    }
    if (rank < 5) idx5[rank] = (unsigned)t;  // stable sort -> first 5 of perm
  }
  if (t < 5) Minv[t] = 1.0f;
  __syncthreads();

  unsigned m = 0;
#pragma unroll
  for (int k = 0; k < 5; k++) m |= (idx5[k] == (unsigned)t) ? (1u << k) : 0u;

  const float* Gc = G + (size_t)c * 65536;
  float s0 = Gc[(size_t)idx5[0] * 256 + t];
  float s1 = Gc[(size_t)idx5[1] * 256 + t];
  float s2 = Gc[(size_t)idx5[2] * 256 + t];
  float s3 = Gc[(size_t)idx5[3] * 256 + t];
  float s4 = Gc[(size_t)idx5[4] * 256 + t];

  for (int it = 0; it < 100; ++it) {
    float v0 = (m & 1u) ? s0 : 0.0f;
    float v1 = (m & 2u) ? s1 : 0.0f;
    float v2 = (m & 4u) ? s2 : 0.0f;
    float v3 = (m & 8u) ? s3 : 0.0f;
    float v4 = (m & 16u) ? s4 : 0.0f;
#pragma unroll
    for (int st = 1; st < 64; st <<= 1) {
      v0 += __shfl_xor(v0, st); v1 += __shfl_xor(v1, st);
      v2 += __shfl_xor(v2, st); v3 += __shfl_xor(v3, st);
      v4 += __shfl_xor(v4, st);
    }
    if (lane == 0) {
      Tpart[w][0] = v0; Tpart[w][1] = v1; Tpart[w][2] = v2;
      Tpart[w][3] = v3; Tpart[w][4] = v4;
    }
    __syncthreads();
    if (t < 5) {
      float T = Tpart[0][t] + Tpart[1][t] + Tpart[2][t] + Tpart[3][t];
      float iv = Minv[t];
      Tu[t] = T * iv * iv;   // |c_k|^2
      C2[t] = -2.0f * iv;    // coefficient on S
    }
    __syncthreads();
    float d0 = fmaf(C2[0], s0, Tu[0]);
    float d1 = fmaf(C2[1], s1, Tu[1]);
    float d2 = fmaf(C2[2], s2, Tu[2]);
    float d3 = fmaf(C2[3], s3, Tu[3]);
    float d4 = fmaf(C2[4], s4, Tu[4]);
    int a_t = 0;
    float dmn = d0;
    if (d1 < dmn) { dmn = d1; a_t = 1; }
    if (d2 < dmn) { dmn = d2; a_t = 2; }
    if (d3 < dmn) { dmn = d3; a_t = 3; }
    if (d4 < dmn) { dmn = d4; a_t = 4; }
#pragma unroll
    for (int k = 0; k < 5; k++) {
      unsigned long long bal = __ballot(a_t == k);
      if (lane == 0) Hp[w][k] = (int)__popcll(bal);
    }
    __syncthreads();
    if (t < 5) Ncnt[t] = Hp[0][t] + Hp[1][t] + Hp[2][t] + Hp[3][t];
    __syncthreads();
    unsigned nm = 0;
#pragma unroll
    for (int k = 0; k < 5; k++) {
      int bit = (Ncnt[k] > 0) ? (a_t == k ? 1 : 0) : (int)((m >> k) & 1u);
      nm |= ((unsigned)bit) << k;
    }
    unsigned dmb = nm ^ m;
    unsigned long long bal = __ballot(dmb != 0);
    int myrank = (int)__popcll(bal & ((1ull << lane) - 1ull));
    if (lane == 0) cntW[w] = (int)__popcll(bal);
    nmL[t] = nm; dmL[t] = dmb;
    __syncthreads();
    int base = 0, ntot = 0;
#pragma unroll
    for (int ww = 0; ww < 4; ww++) {
      int cw = cntW[ww];
      if (ww < w) base += cw;
      ntot += cw;
    }
    if (ntot == 0) break;  // fixed point: remaining iterations are no-ops
    if (dmb != 0) chg[base + myrank] = (unsigned short)t;
    m = nm;
    if (t < 5 && Ncnt[t] > 0) Minv[t] = 1.0f / (float)Ncnt[t];
    __syncthreads();
    for (int p = 0; p < ntot; p += 4) {
      float g[4]; int jj[4];
#pragma unroll
      for (int q = 0; q < 4; q++) {
        int idx = p + q;
        jj[q] = (idx < ntot) ? (int)chg[idx] : -1;
        g[q] = (jj[q] >= 0) ? Gc[(size_t)jj[q] * 256 + t] : 0.0f;
      }
#pragma unroll
      for (int q = 0; q < 4; q++) {
        if (jj[q] < 0) continue;
        unsigned db = dmL[jj[q]], nb = nmL[jj[q]];
        float gv = g[q];
        if (db & 1u)  s0 += (nb & 1u)  ? gv : -gv;
        if (db & 2u)  s1 += (nb & 2u)  ? gv : -gv;
        if (db & 4u)  s2 += (nb & 4u)  ? gv : -gv;
        if (db & 8u)  s3 += (nb & 8u)  ? gv : -gv;
        if (db & 16u) s4 += (nb & 16u) ? gv : -gv;
      }
    }
    __syncthreads();
  }
  float wv = 0.0f;
#pragma unroll
  for (int k = 0; k < 5; k++)
    if ((m >> k) & 1u) wv += 0.2f * Minv[k];
  wts[c * 256 + t] = wv;
}

// ---- 6a. proto partials: 256 blocks (c, 16-row segment) -------------------
__global__ __launch_bounds__(256) void proto1_k(const float* __restrict__ emb,
                                                const float* __restrict__ wts,
                                                float* __restrict__ part) {
  int c = blockIdx.x & 15, seg = blockIdx.x >> 4, t = threadIdx.x;
  __shared__ float wl[16];
  if (t < 16) wl[t] = wts[c * 256 + seg * 16 + t];
  __syncthreads();
  f32x4 acc = {};
  const float* base = emb + (size_t)(c * 256 + seg * 16) * 1024 + t * 4;
#pragma unroll
  for (int j = 0; j < 16; j++) {
    f32x4 v = *(const f32x4*)(base + (size_t)j * 1024);
    float wj = wl[j];
#pragma unroll
    for (int e = 0; e < 4; e++) acc[e] = fmaf(wj, v[e], acc[e]);
  }
  *(f32x4*)(part + ((size_t)seg * 16 + c) * 1024 + t * 4) = acc;
}

// ---- 6b. proto reduce: fixed ascending-seg order (deterministic) ----------
__global__ __launch_bounds__(256) void proto2_k(const float* __restrict__ part,
                                                float* __restrict__ protos) {
  int c = blockIdx.x, t = threadIdx.x;
  f32x4 acc = {};
#pragma unroll
  for (int seg = 0; seg < 16; seg++) {
    f32x4 v = *(const f32x4*)(part + ((size_t)seg * 16 + c) * 1024 + t * 4);
#pragma unroll
    for (int e = 0; e < 4; e++) acc[e] += v[e];
  }
  *(f32x4*)(protos + (size_t)c * 1024 + t * 4) = acc;
}

// ---- 6'. fallback single-kernel proto ------------------------------------
__global__ __launch_bounds__(256) void proto_k(const float* __restrict__ emb,
                                               const float* __restrict__ wts,
                                               float* __restrict__ protos) {
  int c = blockIdx.x, t = threadIdx.x;
  __shared__ float wl[256];
  wl[t] = wts[c * 256 + t];
  __syncthreads();
  f32x4 acc = {};
  const float* base = emb + (size_t)c * 256 * 1024 + t * 4;
  for (int j = 0; j < 256; j++) {
    f32x4 v = *(const f32x4*)(base + (size_t)j * 1024);
    float wj = wl[j];
#pragma unroll
    for (int e = 0; e < 4; e++) acc[e] = fmaf(wj, v[e], acc[e]);
  }
  *(f32x4*)(protos + (size_t)c * 1024 + t * 4) = acc;
}

// ---------------- 7. output: -cdist(query_emb, protos) ---------------------
__global__ __launch_bounds__(256) void dist_k(const float* __restrict__ emb,
                                              const float* __restrict__ protos,
                                              float* __restrict__ out) {
  __shared__ float P[16 * 1024];  // 64 KiB
  int t = threadIdx.x, lane = t & 63, w = t >> 6;
#pragma unroll
  for (int i = 0; i < 16; i++) {
    int off = i * 1024 + t * 4;
    *(f32x4*)(P + off) = *(const f32x4*)(protos + off);
  }
  __syncthreads();
  float psq_keep = 0.0f;
  for (int p = 0; p < 16; p++) {
    float partial = 0.0f;
#pragma unroll
    for (int ch = 0; ch < 16; ch++) {
      float x = P[p * 1024 + ch * 64 + lane];
      partial = fmaf(x, x, partial);
    }
    partial = wave_sum(partial);
    if (lane == p) psq_keep = partial;
  }
  const float* qbase = emb + (size_t)4096 * 1024;
  int r0 = blockIdx.x * 16 + w * 4;
  for (int ri = 0; ri < 4; ri++) {
    int row = r0 + ri;
    const float* q = qbase + (size_t)row * 1024;
    float qv[16];
#pragma unroll
    for (int ch = 0; ch < 16; ch++) qv[ch] = q[ch * 64 + lane];
    float qsq = 0.0f;
#pragma unroll
    for (int ch = 0; ch < 16; ch++) qsq = fmaf(qv[ch], qv[ch], qsq);
    qsq = wave_sum(qsq);
    float dsel = 0.0f;
    for (int p = 0; p < 16; p++) {
      float dp = 0.0f;
#pragma unroll
      for (int ch = 0; ch < 16; ch++)
        dp = fmaf(qv[ch], P[p * 1024 + ch * 64 + lane], dp);
      dp = wave_sum(dp);
      if (lane == p) dsel = dp;
    }
    if (lane < 16) {
      float d2 = qsq - 2.0f * dsel + psq_keep;
      d2 = fmaxf(d2, 0.0f);
      out[(size_t)row * 16 + lane] = -sqrtf(d2);
    }
  }
}

// ---------------- launch ---------------------------------------------------
extern "C" void kernel_launch(void* const* d_in, const int* in_sizes, int n_in,
                              void* d_out, int out_size, void* d_ws,
                              size_t ws_size, hipStream_t stream) {
  const float* sup = (const float*)d_in[0];
  const float* qry = (const float*)d_in[1];
  const float* W = (const float*)d_in[2];
  const float* b = (const float*)d_in[3];
  float* out = (float*)d_out;
  char* ws = (char*)d_ws;
  (void)in_sizes; (void)n_in; (void)out_size;

  const size_t NEED_FAST = 206651392ULL;  // ~197 MiB
  if (ws_size >= NEED_FAST) {
    short* WhiT = (short*)(ws + 0);            //  8 MiB
    short* WloT = (short*)(ws + 8388608);      //  8 MiB
    short* Shi = (short*)(ws + 16777216);      // 32 MiB
    short* Slo = (short*)(ws + 50331648);      // 32 MiB
    short* Qhi = (short*)(ws + 83886080);      // 64 MiB
    float* emb = (float*)(ws + 150994944);     // 48 MiB
    float* G = (float*)(ws + 201326592);       //  4 MiB
    float* wts = (float*)(ws + 205520896);     // 16 KiB
    float* protos = (float*)(ws + 205537280);  // 64 KiB
    float* part = (float*)(ws + 205602816);    //  1 MiB

    prep_k<<<3072, 256, 0, stream>>>(W, sup, qry, WhiT, WloT, Shi, Slo, Qhi);
    gemm_both_k<<<1024, 256, 0, stream>>>(Shi, Slo, Qhi, WhiT, WloT, b, emb);
    gram_k<<<256, 256, 0, stream>>>(emb, G);
    diag_k<<<1024, 256, 0, stream>>>(emb, G);
    kmeans2_k<<<16, 256, 0, stream>>>(G, wts);
    proto1_k<<<256, 256, 0, stream>>>(emb, wts, part);
    proto2_k<<<16, 256, 0, stream>>>(part, protos);
    dist_k<<<512, 256, 0, stream>>>(emb, protos, out);
  } else {
    short* WhiT = (short*)(ws + 0);
    short* WloT = (short*)(ws + 8388608);
    float* emb = (float*)(ws + 16777216);
    float* G = (float*)(ws + 67108864);
    float* wts = (float*)(ws + 71303168);
    float* protos = (float*)(ws + 71319552);

    prep_k<<<1024, 256, 0, stream>>>(W, sup, qry, WhiT, WloT, (short*)0,
                                     (short*)0, (short*)0);
    gemm_all_k<<<768, 256, 0, stream>>>(sup, qry, WhiT, WloT, b, emb);
    gram_k<<<256, 256, 0, stream>>>(emb, G);
    diag_k<<<1024, 256, 0, stream>>>(emb, G);
    kmeans2_k<<<16, 256, 0, stream>>>(G, wts);
    proto_k<<<16, 256, 0, stream>>>(emb, wts, protos);
    dist_k<<<512, 256, 0, stream>>>(emb, protos, out);
  }
}

// Round 10
// 452.499 us; speedup vs baseline: 1.0140x; 1.0140x over previous
//
#include <hip/hip_runtime.h>
#include <cstdint>
#include <cstddef>

// ClusterProtoNetwork: pre-converted bf16 operands -> split encoder GEMMs
// (sup: BM=64 3-product, 3 blk/CU; qry: BM=128 1-product, 5 blk/CU) ->
// merged gram+diag -> one-wave-per-class kmeans (zero barriers, incremental
// fp32 S) -> protos (2-stage) -> cdist.  JAX threefry (partitionable).

typedef __attribute__((ext_vector_type(4))) float f32x4;
typedef __attribute__((ext_vector_type(8))) short s16x8;
typedef __attribute__((ext_vector_type(4))) short s16x4;
typedef __attribute__((ext_vector_type(8))) __bf16 bf16x8;

__device__ __forceinline__ unsigned short f2bf(float f) {
  unsigned u = __float_as_uint(f);
  return (unsigned short)((u + 0x7FFFu + ((u >> 16) & 1u)) >> 16);  // RTNE
}
__device__ __forceinline__ float bf2f(unsigned short h) {
  return __uint_as_float(((unsigned)h) << 16);
}

typedef const __attribute__((address_space(1))) void GV;
typedef __attribute__((address_space(3))) void LV;
__device__ __forceinline__ void gload_lds16(const void* g, void* l) {
  __builtin_amdgcn_global_load_lds((GV*)g, (LV*)l, 16, 0, 0);
}
__device__ __forceinline__ f32x4 mfma16(bf16x8 a, bf16x8 b, f32x4 c) {
  return __builtin_amdgcn_mfma_f32_16x16x32_bf16(a, b, c, 0, 0, 0);
}
__device__ __forceinline__ float wave_sum(float v) {
#pragma unroll
  for (int st = 1; st < 64; st <<= 1) v += __shfl_xor(v, st);
  return v;
}

// ---------------- Threefry-2x32 (JAX-exact, 20 rounds) ----------------
__device__ __forceinline__ void tf2x32(unsigned k0, unsigned k1, unsigned x0,
                                       unsigned x1, unsigned& y0, unsigned& y1) {
  unsigned ks0 = k0, ks1 = k1, ks2 = k0 ^ k1 ^ 0x1BD11BDAu;
  x0 += ks0; x1 += ks1;
  const int rA[4] = {13, 15, 26, 6};
  const int rB[4] = {17, 29, 16, 24};
#define ROTL(v, d) (((v) << (d)) | ((v) >> (32 - (d))))
#define RG(R)                                     \
  _Pragma("unroll") for (int i = 0; i < 4; i++) { \
    x0 += x1; x1 = ROTL(x1, R[i]); x1 ^= x0;      \
  }
  RG(rA); x0 += ks1; x1 += ks2 + 1u;
  RG(rB); x0 += ks2; x1 += ks0 + 2u;
  RG(rA); x0 += ks0; x1 += ks1 + 3u;
  RG(rB); x0 += ks1; x1 += ks2 + 4u;
  RG(rA); x0 += ks2; x1 += ks0 + 5u;
#undef RG
#undef ROTL
  y0 = x0; y1 = x1;
}

// ---- 1. merged prep: W -> WhiT/WloT (transposed split); sup/qry -> bf16 ---
__global__ __launch_bounds__(256) void prep_k(
    const float* __restrict__ W, const float* __restrict__ sup,
    const float* __restrict__ qry, short* __restrict__ WhiT,
    short* __restrict__ WloT, short* __restrict__ Shi,
    short* __restrict__ Slo, short* __restrict__ Qhi) {
  __shared__ float tile[64][65];
  int t = threadIdx.x;
  if (blockIdx.x < 1024) {  // prepw: 64 k-tiles x 16 n-tiles of 64x64
    int bk = blockIdx.x & 63, bn = blockIdx.x >> 6;
#pragma unroll
    for (int i = 0; i < 4; i++) {
      int row = i * 16 + (t >> 4);
      int col = (t & 15) * 4;
      f32x4 v =
          *(const f32x4*)(W + (size_t)(bk * 64 + row) * 1024 + bn * 64 + col);
      tile[row][col + 0] = v[0]; tile[row][col + 1] = v[1];
      tile[row][col + 2] = v[2]; tile[row][col + 3] = v[3];
    }
    __syncthreads();
#pragma unroll
    for (int i = 0; i < 4; i++) {
      int nrow = i * 16 + (t >> 4);
      int kcol = (t & 15) * 4;
      s16x4 hv, lv;
#pragma unroll
      for (int e = 0; e < 4; e++) {
        float v = tile[kcol + e][nrow];
        unsigned short h = f2bf(v);
        hv[e] = (short)h;
        lv[e] = (short)f2bf(v - bf2f(h));
      }
      size_t off = (size_t)(bn * 64 + nrow) * 4096 + bk * 64 + kcol;
      *(s16x4*)(WhiT + off) = hv;
      *(s16x4*)(WloT + off) = lv;
    }
  } else {  // prepa: grid-stride over 6M 8-elem chunks
    const size_t sup_n8 = (size_t)4096 * 4096 / 8;           // 2M
    const size_t tot_n8 = sup_n8 + (size_t)8192 * 4096 / 8;  // 6M
    size_t stride = (size_t)(gridDim.x - 1024) * 256;
    for (size_t gid = (size_t)(blockIdx.x - 1024) * 256 + t; gid < tot_n8;
         gid += stride) {
      if (gid < sup_n8) {
        const float* src = sup + gid * 8;
        f32x4 v0 = *(const f32x4*)src, v1 = *(const f32x4*)(src + 4);
        s16x8 h, l;
#pragma unroll
        for (int e = 0; e < 4; e++) {
          unsigned short hh = f2bf(v0[e]);
          h[e] = (short)hh; l[e] = (short)f2bf(v0[e] - bf2f(hh));
        }
#pragma unroll
        for (int e = 0; e < 4; e++) {
          unsigned short hh = f2bf(v1[e]);
          h[4 + e] = (short)hh; l[4 + e] = (short)f2bf(v1[e] - bf2f(hh));
        }
        *(s16x8*)(Shi + gid * 8) = h;
        *(s16x8*)(Slo + gid * 8) = l;
      } else {
        size_t q = gid - sup_n8;
        const float* src = qry + q * 8;
        f32x4 v0 = *(const f32x4*)src, v1 = *(const f32x4*)(src + 4);
        s16x8 h;
#pragma unroll
        for (int e = 0; e < 4; e++) h[e] = (short)f2bf(v0[e]);
#pragma unroll
        for (int e = 0; e < 4; e++) h[4 + e] = (short)f2bf(v1[e]);
        *(s16x8*)(Qhi + q * 8) = h;
      }
    }
  }
}

// ---- 2a. support GEMM: BM=64, 3-product hi/lo, 48 KiB LDS (3 blk/CU) ------
__global__ __launch_bounds__(256) void gemm_sup_k(
    const short* __restrict__ Shi, const short* __restrict__ Slo,
    const short* __restrict__ WhiT, const short* __restrict__ WloT,
    const float* __restrict__ bias, float* __restrict__ emb) {
  __shared__ short lds[24576];  // 48 KiB
  short* Ah = lds;              // [64][64]
  short* Al = lds + 4096;       // [64][64]
  short* Bh = lds + 8192;       // [128][64]
  short* Bl = lds + 16384;      // [128][64]
  const int bid = blockIdx.x;
  const int bm = bid & 63, bn = bid >> 6;  // siblings +64 -> same XCD
  const int t = threadIdx.x, lane = t & 63, w = t >> 6;
  const int wr = w >> 1, wc = w & 1;  // wave tile 32 x 64
  const int fr = lane & 15, kg = lane >> 4;
  const int ls = lane >> 3, lc = lane & 7;
  const short* Ag = Shi + (size_t)bm * 64 * 4096;
  const short* Alg = Slo + (size_t)bm * 64 * 4096;
  f32x4 acc[2][4] = {};

  for (int kt = 0; kt < 64; ++kt) {
    const int k0 = kt * 64;
    __syncthreads();
    const int cch = (lc ^ ls) * 8;
#pragma unroll
    for (int j = 0; j < 2; j++) {
      int rowl = w * 16 + j * 8 + ls;
      size_t aoff = (size_t)rowl * 4096 + k0 + cch;
      int ldst = (w * 16 + j * 8) * 64;
      gload_lds16(Ag + aoff, Ah + ldst);
      gload_lds16(Alg + aoff, Al + ldst);
    }
#pragma unroll
    for (int j = 0; j < 4; j++) {
      int rowl = w * 32 + j * 8 + ls;
      size_t boff = (size_t)(bn * 128 + rowl) * 4096 + k0 + cch;
      int ldst = (w * 32 + j * 8) * 64;
      gload_lds16(WhiT + boff, Bh + ldst);
      gload_lds16(WloT + boff, Bl + ldst);
    }
    __syncthreads();
#pragma unroll
    for (int ks = 0; ks < 2; ++ks) {
      const int cx = ((ks * 4 + kg) ^ (fr & 7)) * 8;
      bf16x8 ahf[2], alf[2], bhf[4], blf[4];
#pragma unroll
      for (int mi = 0; mi < 2; mi++) {
        int arow = wr * 32 + mi * 16 + fr;
        ahf[mi] = __builtin_bit_cast(bf16x8, *(const s16x8*)(Ah + arow * 64 + cx));
        alf[mi] = __builtin_bit_cast(bf16x8, *(const s16x8*)(Al + arow * 64 + cx));
      }
#pragma unroll
      for (int ni = 0; ni < 4; ni++) {
        int brow = wc * 64 + ni * 16 + fr;
        bhf[ni] = __builtin_bit_cast(bf16x8, *(const s16x8*)(Bh + brow * 64 + cx));
        blf[ni] = __builtin_bit_cast(bf16x8, *(const s16x8*)(Bl + brow * 64 + cx));
      }
#pragma unroll
      for (int mi = 0; mi < 2; mi++)
#pragma unroll
        for (int ni = 0; ni < 4; ni++) {
          acc[mi][ni] = mfma16(ahf[mi], bhf[ni], acc[mi][ni]);
          acc[mi][ni] = mfma16(ahf[mi], blf[ni], acc[mi][ni]);
          acc[mi][ni] = mfma16(alf[mi], bhf[ni], acc[mi][ni]);
        }
    }
  }
#pragma unroll
  for (int ni = 0; ni < 4; ni++) {
    int gc = bn * 128 + wc * 64 + ni * 16 + fr;
    float bv = bias[gc];
#pragma unroll
    for (int mi = 0; mi < 2; mi++) {
      int gr = bm * 64 + wr * 32 + mi * 16 + kg * 4;
#pragma unroll
      for (int r = 0; r < 4; r++)
        emb[(size_t)(gr + r) * 1024 + gc] = acc[mi][ni][r] + bv;
    }
  }
}

// ---- 2b. query GEMM: BM=128, 1-product, 32 KiB LDS (5 blk/CU) -------------
__global__ __launch_bounds__(256) void gemm_qry_k(
    const short* __restrict__ Qhi, const short* __restrict__ WhiT,
    const float* __restrict__ bias, float* __restrict__ emb) {
  __shared__ short lds[16384];  // 32 KiB: Ah[128][64], Bh[128][64]
  short* Ah = lds;
  short* Bh = lds + 8192;
  const int bid = blockIdx.x;
  const int bm = bid & 63, bn = bid >> 6;  // siblings +64 -> same XCD
  const int t = threadIdx.x, lane = t & 63, w = t >> 6;
  const int wr = w >> 1, wc = w & 1;
  const int fr = lane & 15, kg = lane >> 4;
  const int ls = lane >> 3, lc = lane & 7;
  const short* Ag = Qhi + (size_t)bm * 128 * 4096;
  f32x4 acc[4][4] = {};

  for (int kt = 0; kt < 64; ++kt) {
    const int k0 = kt * 64;
    __syncthreads();
    const int cch = (lc ^ ls) * 8;
#pragma unroll
    for (int j = 0; j < 4; j++) {
      int rowl = w * 32 + j * 8 + ls;
      size_t aoff = (size_t)rowl * 4096 + k0 + cch;
      size_t boff = (size_t)(bn * 128 + rowl) * 4096 + k0 + cch;
      int ldst = (w * 32 + j * 8) * 64;
      gload_lds16(Ag + aoff, Ah + ldst);
      gload_lds16(WhiT + boff, Bh + ldst);
    }
    __syncthreads();
#pragma unroll
    for (int ks = 0; ks < 2; ++ks) {
      const int cx = ((ks * 4 + kg) ^ (fr & 7)) * 8;
      bf16x8 ahf[4], bhf[4];
#pragma unroll
      for (int mi = 0; mi < 4; mi++) {
        int arow = wr * 64 + mi * 16 + fr;
        ahf[mi] = __builtin_bit_cast(bf16x8, *(const s16x8*)(Ah + arow * 64 + cx));
      }
#pragma unroll
      for (int ni = 0; ni < 4; ni++) {
        int brow = wc * 64 + ni * 16 + fr;
        bhf[ni] = __builtin_bit_cast(bf16x8, *(const s16x8*)(Bh + brow * 64 + cx));
      }
#pragma unroll
      for (int mi = 0; mi < 4; mi++)
#pragma unroll
        for (int ni = 0; ni < 4; ni++)
          acc[mi][ni] = mfma16(ahf[mi], bhf[ni], acc[mi][ni]);
    }
  }
#pragma unroll
  for (int ni = 0; ni < 4; ni++) {
    int gc = bn * 128 + wc * 64 + ni * 16 + fr;
    float bv = bias[gc];
#pragma unroll
    for (int mi = 0; mi < 4; mi++) {
      int gr = 4096 + bm * 128 + wr * 64 + mi * 16 + kg * 4;
#pragma unroll
      for (int r = 0; r < 4; r++)
        emb[(size_t)(gr + r) * 1024 + gc] = acc[mi][ni][r] + bv;
    }
  }
}

// ---- 2'. fallback GEMM (in-loop convert; used when ws too small) ----------
__global__ __launch_bounds__(256) void gemm_all_k(
    const float* __restrict__ sup, const float* __restrict__ qry,
    const short* __restrict__ WhiT, const short* __restrict__ WloT,
    const float* __restrict__ bias, float* __restrict__ emb) {
  __shared__ short lds[4 * 128 * 64];
  short* Ah = lds;
  short* Al = lds + 8192;
  short* Bh = lds + 16384;
  short* Bl = lds + 24576;
  const int bid = blockIdx.x;
  const int bm = bid % 96, bn = bid / 96;
  const bool is_sup = bm < 32;
  const int t = threadIdx.x, lane = t & 63, w = t >> 6;
  const int wr = w >> 1, wc = w & 1;
  const int fr = lane & 15, kg = lane >> 4;
  const float* Abase = is_sup ? (sup + (size_t)bm * 128 * 4096)
                              : (qry + (size_t)(bm - 32) * 128 * 4096);
  f32x4 acc[4][4] = {};
  const int ls = lane >> 3, lc = lane & 7;

  for (int kt = 0; kt < 64; ++kt) {
    const int k0 = kt * 64;
    __syncthreads();
#pragma unroll
    for (int i = 0; i < 4; i++) {
      int row = i * 32 + w * 8 + ls;
      const float* src = Abase + (size_t)row * 4096 + k0 + lc * 8;
      f32x4 v0 = *(const f32x4*)src;
      f32x4 v1 = *(const f32x4*)(src + 4);
      s16x8 hs;
#pragma unroll
      for (int e = 0; e < 4; e++) hs[e] = (short)f2bf(v0[e]);
#pragma unroll
      for (int e = 0; e < 4; e++) hs[4 + e] = (short)f2bf(v1[e]);
      int chunk = lc ^ (row & 7);
      *(s16x8*)(Ah + row * 64 + chunk * 8) = hs;
      if (is_sup) {
        s16x8 lsv;
#pragma unroll
        for (int e = 0; e < 4; e++)
          lsv[e] = (short)f2bf(v0[e] - bf2f((unsigned short)hs[e]));
#pragma unroll
        for (int e = 0; e < 4; e++)
          lsv[4 + e] = (short)f2bf(v1[e] - bf2f((unsigned short)hs[4 + e]));
        *(s16x8*)(Al + row * 64 + chunk * 8) = lsv;
      }
    }
#pragma unroll
    for (int j = 0; j < 4; j++) {
      int rowl = w * 32 + j * 8 + ls;
      int cch = (lc ^ (ls & 7)) * 8;
      size_t goff = (size_t)(bn * 128 + rowl) * 4096 + k0 + cch;
      gload_lds16(WhiT + goff, Bh + (w * 32 + j * 8) * 64);
      if (is_sup) gload_lds16(WloT + goff, Bl + (w * 32 + j * 8) * 64);
    }
    __syncthreads();
#pragma unroll
    for (int ks = 0; ks < 2; ++ks) {
      const int cx = ((ks * 4 + kg) ^ (fr & 7)) * 8;
      bf16x8 ahf[4], bhf[4];
#pragma unroll
      for (int mi = 0; mi < 4; mi++) {
        int arow = wr * 64 + mi * 16 + fr;
        ahf[mi] = __builtin_bit_cast(bf16x8, *(const s16x8*)(Ah + arow * 64 + cx));
      }
#pragma unroll
      for (int ni = 0; ni < 4; ni++) {
        int brow = wc * 64 + ni * 16 + fr;
        bhf[ni] = __builtin_bit_cast(bf16x8, *(const s16x8*)(Bh + brow * 64 + cx));
      }
      if (is_sup) {
        bf16x8 alf[4], blf[4];
#pragma unroll
        for (int mi = 0; mi < 4; mi++) {
          int arow = wr * 64 + mi * 16 + fr;
          alf[mi] =
              __builtin_bit_cast(bf16x8, *(const s16x8*)(Al + arow * 64 + cx));
        }
#pragma unroll
        for (int ni = 0; ni < 4; ni++) {
          int brow = wc * 64 + ni * 16 + fr;
          blf[ni] =
              __builtin_bit_cast(bf16x8, *(const s16x8*)(Bl + brow * 64 + cx));
        }
#pragma unroll
        for (int mi = 0; mi < 4; mi++)
#pragma unroll
          for (int ni = 0; ni < 4; ni++) {
            acc[mi][ni] = mfma16(ahf[mi], bhf[ni], acc[mi][ni]);
            acc[mi][ni] = mfma16(ahf[mi], blf[ni], acc[mi][ni]);
            acc[mi][ni] = mfma16(alf[mi], bhf[ni], acc[mi][ni]);
          }
      } else {
#pragma unroll
        for (int mi = 0; mi < 4; mi++)
#pragma unroll
          for (int ni = 0; ni < 4; ni++)
            acc[mi][ni] = mfma16(ahf[mi], bhf[ni], acc[mi][ni]);
      }
    }
  }
#pragma unroll
  for (int ni = 0; ni < 4; ni++) {
    int gc = bn * 128 + wc * 64 + ni * 16 + fr;
    float bv = bias[gc];
#pragma unroll
    for (int mi = 0; mi < 4; mi++) {
      int gr = bm * 128 + wr * 64 + mi * 16 + kg * 4;
#pragma unroll
      for (int r = 0; r < 4; r++)
        emb[(size_t)(gr + r) * 1024 + gc] = acc[mi][ni][r] + bv;
    }
  }
}

// ---- 3. merged gram (skip-diag) + f64-exact diagonal, one launch ----------
// blocks [0,256): gram 64x64 tiles, diagonal stores skipped (disjoint from
// diag blocks -> no race); blocks [256,1280): diag rows (4 per block).
__global__ __launch_bounds__(256) void gramdiag_k(const float* __restrict__ emb,
                                                  float* __restrict__ G) {
  if (blockIdx.x < 256) {
    int c = blockIdx.x >> 4, tl = blockIdx.x & 15, ti = tl >> 2, tj = tl & 3;
    __shared__ float As[64][36];
    __shared__ float Bs[32][68];
    int t = threadIdx.x, ty = t >> 4, tx = t & 15;
    const float* base = emb + (size_t)c * 256 * 1024;
    float acc[4][4] = {};
    for (int k0 = 0; k0 < 1024; k0 += 32) {
      __syncthreads();
      {
        int r = t >> 2, seg = t & 3;
        const float* pa = base + (size_t)(ti * 64 + r) * 1024 + k0 + seg * 8;
        f32x4 va0 = *(const f32x4*)pa, va1 = *(const f32x4*)(pa + 4);
        *(f32x4*)(&As[r][seg * 8]) = va0;
        *(f32x4*)(&As[r][seg * 8 + 4]) = va1;
        const float* pb = base + (size_t)(tj * 64 + r) * 1024 + k0 + seg * 8;
        f32x4 vb0 = *(const f32x4*)pb, vb1 = *(const f32x4*)(pb + 4);
#pragma unroll
        for (int e = 0; e < 4; e++) Bs[seg * 8 + e][r] = vb0[e];
#pragma unroll
        for (int e = 0; e < 4; e++) Bs[seg * 8 + 4 + e][r] = vb1[e];
      }
      __syncthreads();
#pragma unroll 4
      for (int kk = 0; kk < 32; kk++) {
        float a0 = As[ty * 4 + 0][kk], a1 = As[ty * 4 + 1][kk];
        float a2 = As[ty * 4 + 2][kk], a3 = As[ty * 4 + 3][kk];
        f32x4 bv = *(const f32x4*)(&Bs[kk][tx * 4]);
#pragma unroll
        for (int jdx = 0; jdx < 4; jdx++) {
          acc[0][jdx] = fmaf(a0, bv[jdx], acc[0][jdx]);
          acc[1][jdx] = fmaf(a1, bv[jdx], acc[1][jdx]);
          acc[2][jdx] = fmaf(a2, bv[jdx], acc[2][jdx]);
          acc[3][jdx] = fmaf(a3, bv[jdx], acc[3][jdx]);
        }
      }
    }
#pragma unroll
    for (int i = 0; i < 4; i++) {
      int gr = ti * 64 + ty * 4 + i;
#pragma unroll
      for (int j = 0; j < 4; j++) {
        int gcl = tj * 64 + tx * 4 + j;
        if (gr != gcl)  // diagonal owned by the diag blocks
          G[(size_t)c * 65536 + (size_t)gr * 256 + gcl] = acc[i][j];
      }
    }
  } else {
    int r = (blockIdx.x - 256) * 4 + (threadIdx.x >> 6);  // support row
    int lane = threadIdx.x & 63;
    const float* x = emb + (size_t)r * 1024;
    double acc = 0.0;
#pragma unroll
    for (int ch = 0; ch < 16; ch++) {
      float v = x[ch * 64 + lane];
      acc = fma((double)v, (double)v, acc);
    }
#pragma unroll
    for (int st = 1; st < 64; st <<= 1) acc += __shfl_xor(acc, st);
    if (lane == 0) {
      int c = r >> 8, i = r & 255;
      G[(size_t)c * 65536 + (size_t)i * 256 + i] = (float)acc;
    }
  }
}

// ---- 4. one-wave-per-class kmeans: 64 threads, 4 points/lane, 0 barriers --
#define APPLY1(db, nb, gg, p)                        \
  if ((db) & 1u)  s[p][0] += ((nb) & 1u)  ? (gg) : -(gg); \
  if ((db) & 2u)  s[p][1] += ((nb) & 2u)  ? (gg) : -(gg); \
  if ((db) & 4u)  s[p][2] += ((nb) & 4u)  ? (gg) : -(gg); \
  if ((db) & 8u)  s[p][3] += ((nb) & 8u)  ? (gg) : -(gg); \
  if ((db) & 16u) s[p][4] += ((nb) & 16u) ? (gg) : -(gg);

__global__ __launch_bounds__(64) void kmeans3_k(const float* __restrict__ G,
                                                float* __restrict__ wts) {
  const int c = blockIdx.x;
  const int lane = threadIdx.x;  // one wave per class
  // --- RNG (threefry partitionable): sortkey per point, xor-fold
  unsigned o0, o1, s0k, s1k;
  tf2x32(0u, 42u, 0u, (unsigned)c, o0, o1);
  tf2x32(o0, o1, 0u, 1u, s0k, s1k);
  unsigned long long key[4];
#pragma unroll
  for (int q = 0; q < 4; q++) {
    unsigned y0, y1;
    tf2x32(s0k, s1k, 0u, (unsigned)(lane + 64 * q), y0, y1);
    key[q] = ((unsigned long long)(y0 ^ y1) << 32) | (unsigned)(lane + 64 * q);
  }
  // --- 5 smallest (value, index) keys = stable-first-5 of argsort
  int idx5[5];
#pragma unroll
  for (int r = 0; r < 5; r++) {
    unsigned long long mn = key[0];
#pragma unroll
    for (int q = 1; q < 4; q++) mn = key[q] < mn ? key[q] : mn;
#pragma unroll
    for (int st = 1; st < 64; st <<= 1) {
      unsigned long long o = __shfl_xor(mn, st);
      mn = o < mn ? o : mn;
    }
    int widx = (int)(unsigned)(mn & 0xffffffffu);
    idx5[r] = widx;
#pragma unroll
    for (int q = 0; q < 4; q++)
      if (widx == lane + 64 * q) key[q] = ~0ull;
  }
  unsigned m[4];
#pragma unroll
  for (int q = 0; q < 4; q++) {
    unsigned mm = 0;
#pragma unroll
    for (int k = 0; k < 5; k++)
      if (idx5[k] == lane + 64 * q) mm |= 1u << k;
    m[q] = mm;
  }
  const float* Gc = G + (size_t)c * 65536;
  float s[4][5];
#pragma unroll
  for (int k = 0; k < 5; k++) {
    const float* row = Gc + (size_t)idx5[k] * 256;
#pragma unroll
    for (int q = 0; q < 4; q++) s[q][k] = row[lane + 64 * q];
  }
  float Minv[5] = {1.0f, 1.0f, 1.0f, 1.0f, 1.0f};

  for (int it = 0; it < 100; ++it) {
    // T_k = sum of member S (wave allreduce)
    float Tu[5], C2[5];
#pragma unroll
    for (int k = 0; k < 5; k++) {
      float v = 0.0f;
#pragma unroll
      for (int q = 0; q < 4; q++)
        v += ((m[q] >> k) & 1u) ? s[q][k] : 0.0f;
#pragma unroll
      for (int st = 1; st < 64; st <<= 1) v += __shfl_xor(v, st);
      float iv = Minv[k];
      Tu[k] = v * iv * iv;
      C2[k] = -2.0f * iv;
    }
    // assignment (first-min), per point
    int a[4];
#pragma unroll
    for (int q = 0; q < 4; q++) {
      float d0 = fmaf(C2[0], s[q][0], Tu[0]);
      float d1 = fmaf(C2[1], s[q][1], Tu[1]);
      float d2 = fmaf(C2[2], s[q][2], Tu[2]);
      float d3 = fmaf(C2[3], s[q][3], Tu[3]);
      float d4 = fmaf(C2[4], s[q][4], Tu[4]);
      int at = 0;
      float dmn = d0;
      if (d1 < dmn) { dmn = d1; at = 1; }
      if (d2 < dmn) { dmn = d2; at = 2; }
      if (d3 < dmn) { dmn = d3; at = 3; }
      if (d4 < dmn) { dmn = d4; at = 4; }
      a[q] = at;
    }
    int cnt[5];
#pragma unroll
    for (int k = 0; k < 5; k++) {
      int v = (a[0] == k) + (a[1] == k) + (a[2] == k) + (a[3] == k);
#pragma unroll
      for (int st = 1; st < 64; st <<= 1) v += __shfl_xor(v, st);
      cnt[k] = v;
    }
    unsigned nm[4], dm[4];
#pragma unroll
    for (int q = 0; q < 4; q++) {
      unsigned nv = 0;
#pragma unroll
      for (int k = 0; k < 5; k++) {
        int bit = (cnt[k] > 0) ? (a[q] == k ? 1 : 0) : (int)((m[q] >> k) & 1u);
        nv |= ((unsigned)bit) << k;
      }
      nm[q] = nv;
      dm[q] = nv ^ m[q];
    }
    unsigned long long bal[4];
#pragma unroll
    for (int q = 0; q < 4; q++) bal[q] = __ballot(dm[q] != 0);
    if ((bal[0] | bal[1] | bal[2] | bal[3]) == 0) break;  // fixed point
#pragma unroll
    for (int q = 0; q < 4; q++) m[q] = nm[q];
#pragma unroll
    for (int k = 0; k < 5; k++)
      if (cnt[k] > 0) Minv[k] = 1.0f / (float)cnt[k];
    // apply S updates, ascending point order, 8-deep static chunks
#pragma unroll
    for (int q = 0; q < 4; q++) {
      unsigned long long mask = bal[q];
      while (mask) {
#define GATHER(i)                                                      \
        int j##i = -1;                                                 \
        unsigned d##i = 0, e##i = 0;                                   \
        float g##i##0 = 0, g##i##1 = 0, g##i##2 = 0, g##i##3 = 0;      \
        if (mask) {                                                    \
          j##i = __builtin_ctzll(mask);                                \
          mask &= mask - 1;                                            \
          d##i = __shfl(dm[q], j##i);                                  \
          e##i = __shfl(nm[q], j##i);                                  \
          const float* row = Gc + (size_t)(q * 64 + j##i) * 256 + lane;\
          g##i##0 = row[0];  g##i##1 = row[64];                        \
          g##i##2 = row[128]; g##i##3 = row[192];                      \
        }
        GATHER(0) GATHER(1) GATHER(2) GATHER(3)
        GATHER(4) GATHER(5) GATHER(6) GATHER(7)
#undef GATHER
#define DOAPPLY(i)                        \
        if (j##i >= 0) {                  \
          APPLY1(d##i, e##i, g##i##0, 0)  \
          APPLY1(d##i, e##i, g##i##1, 1)  \
          APPLY1(d##i, e##i, g##i##2, 2)  \
          APPLY1(d##i, e##i, g##i##3, 3)  \
        }
        DOAPPLY(0) DOAPPLY(1) DOAPPLY(2) DOAPPLY(3)
        DOAPPLY(4) DOAPPLY(5) DOAPPLY(6) DOAPPLY(7)
#undef DOAPPLY
      }
    }
  }
  // final weights
#pragma unroll
  for (int q = 0; q < 4; q++) {
    float wv = 0.0f;
#pragma unroll
    for (int k = 0; k < 5; k++)
      if ((m[q] >> k) & 1u) wv += 0.2f * Minv[k];
    wts[c * 256 + lane + 64 * q] = wv;
  }
}

// ---- 6a. proto partials: 256 blocks (c, 16-row segment) -------------------
__global__ __launch_bounds__(256) void proto1_k(const float* __restrict__ emb,
                                                const float* __restrict__ wts,
                                                float* __restrict__ part) {
  int c = blockIdx.x & 15, seg = blockIdx.x >> 4, t = threadIdx.x;
  __shared__ float wl[16];
  if (t < 16) wl[t] = wts[c * 256 + seg * 16 + t];
  __syncthreads();
  f32x4 acc = {};
  const float* base = emb + (size_t)(c * 256 + seg * 16) * 1024 + t * 4;
#pragma unroll
  for (int j = 0; j < 16; j++) {
    f32x4 v = *(const f32x4*)(base + (size_t)j * 1024);
    float wj = wl[j];
#pragma unroll
    for (int e = 0; e < 4; e++) acc[e] = fmaf(wj, v[e], acc[e]);
  }
  *(f32x4*)(part + ((size_t)seg * 16 + c) * 1024 + t * 4) = acc;
}

// ---- 6b. proto reduce: fixed ascending-seg order (deterministic) ----------
__global__ __launch_bounds__(256) void proto2_k(const float* __restrict__ part,
                                                float* __restrict__ protos) {
  int c = blockIdx.x, t = threadIdx.x;
  f32x4 acc = {};
#pragma unroll
  for (int seg = 0; seg < 16; seg++) {
    f32x4 v = *(const f32x4*)(part + ((size_t)seg * 16 + c) * 1024 + t * 4);
#pragma unroll
    for (int e = 0; e < 4; e++) acc[e] += v[e];
  }
  *(f32x4*)(protos + (size_t)c * 1024 + t * 4) = acc;
}

// ---- 6'. fallback single-kernel proto ------------------------------------
__global__ __launch_bounds__(256) void proto_k(const float* __restrict__ emb,
                                               const float* __restrict__ wts,
                                               float* __restrict__ protos) {
  int c = blockIdx.x, t = threadIdx.x;
  __shared__ float wl[256];
  wl[t] = wts[c * 256 + t];
  __syncthreads();
  f32x4 acc = {};
  const float* base = emb + (size_t)c * 256 * 1024 + t * 4;
  for (int j = 0; j < 256; j++) {
    f32x4 v = *(const f32x4*)(base + (size_t)j * 1024);
    float wj = wl[j];
#pragma unroll
    for (int e = 0; e < 4; e++) acc[e] = fmaf(wj, v[e], acc[e]);
  }
  *(f32x4*)(protos + (size_t)c * 1024 + t * 4) = acc;
}

// ---------------- 7. output: -cdist(query_emb, protos) ---------------------
__global__ __launch_bounds__(256) void dist_k(const float* __restrict__ emb,
                                              const float* __restrict__ protos,
                                              float* __restrict__ out) {
  __shared__ float P[16 * 1024];  // 64 KiB
  int t = threadIdx.x, lane = t & 63, w = t >> 6;
#pragma unroll
  for (int i = 0; i < 16; i++) {
    int off = i * 1024 + t * 4;
    *(f32x4*)(P + off) = *(const f32x4*)(protos + off);
  }
  __syncthreads();
  float psq_keep = 0.0f;
  for (int p = 0; p < 16; p++) {
    float partial = 0.0f;
#pragma unroll
    for (int ch = 0; ch < 16; ch++) {
      float x = P[p * 1024 + ch * 64 + lane];
      partial = fmaf(x, x, partial);
    }
    partial = wave_sum(partial);
    if (lane == p) psq_keep = partial;
  }
  const float* qbase = emb + (size_t)4096 * 1024;
  int r0 = blockIdx.x * 16 + w * 4;
  for (int ri = 0; ri < 4; ri++) {
    int row = r0 + ri;
    const float* q = qbase + (size_t)row * 1024;
    float qv[16];
#pragma unroll
    for (int ch = 0; ch < 16; ch++) qv[ch] = q[ch * 64 + lane];
    float qsq = 0.0f;
#pragma unroll
    for (int ch = 0; ch < 16; ch++) qsq = fmaf(qv[ch], qv[ch], qsq);
    qsq = wave_sum(qsq);
    float dsel = 0.0f;
    for (int p = 0; p < 16; p++) {
      float dp = 0.0f;
#pragma unroll
      for (int ch = 0; ch < 16; ch++)
        dp = fmaf(qv[ch], P[p * 1024 + ch * 64 + lane], dp);
      dp = wave_sum(dp);
      if (lane == p) dsel = dp;
    }
    if (lane < 16) {
      float d2 = qsq - 2.0f * dsel + psq_keep;
      d2 = fmaxf(d2, 0.0f);
      out[(size_t)row * 16 + lane] = -sqrtf(d2);
    }
  }
}

// ---------------- launch ---------------------------------------------------
extern "C" void kernel_launch(void* const* d_in, const int* in_sizes, int n_in,
                              void* d_out, int out_size, void* d_ws,
                              size_t ws_size, hipStream_t stream) {
  const float* sup = (const float*)d_in[0];
  const float* qry = (const float*)d_in[1];
  const float* W = (const float*)d_in[2];
  const float* b = (const float*)d_in[3];
  float* out = (float*)d_out;
  char* ws = (char*)d_ws;
  (void)in_sizes; (void)n_in; (void)out_size;

  const size_t NEED_FAST = 206651392ULL;  // ~197 MiB
  if (ws_size >= NEED_FAST) {
    short* WhiT = (short*)(ws + 0);            //  8 MiB
    short* WloT = (short*)(ws + 8388608);      //  8 MiB
    short* Shi = (short*)(ws + 16777216);      // 32 MiB
    short* Slo = (short*)(ws + 50331648);      // 32 MiB
    short* Qhi = (short*)(ws + 83886080);      // 64 MiB
    float* emb = (float*)(ws + 150994944);     // 48 MiB
    float* G = (float*)(ws + 201326592);       //  4 MiB
    float* wts = (float*)(ws + 205520896);     // 16 KiB
    float* protos = (float*)(ws + 205537280);  // 64 KiB
    float* part = (float*)(ws + 205602816);    //  1 MiB

    prep_k<<<3072, 256, 0, stream>>>(W, sup, qry, WhiT, WloT, Shi, Slo, Qhi);
    gemm_sup_k<<<512, 256, 0, stream>>>(Shi, Slo, WhiT, WloT, b, emb);
    gemm_qry_k<<<512, 256, 0, stream>>>(Qhi, WhiT, b, emb);
    gramdiag_k<<<1280, 256, 0, stream>>>(emb, G);
    kmeans3_k<<<16, 64, 0, stream>>>(G, wts);
    proto1_k<<<256, 256, 0, stream>>>(emb, wts, part);
    proto2_k<<<16, 256, 0, stream>>>(part, protos);
    dist_k<<<512, 256, 0, stream>>>(emb, protos, out);
  } else {
    short* WhiT = (short*)(ws + 0);
    short* WloT = (short*)(ws + 8388608);
    float* emb = (float*)(ws + 16777216);
    float* G = (float*)(ws + 67108864);
    float* wts = (float*)(ws + 71303168);
    float* protos = (float*)(ws + 71319552);

    prep_k<<<1024, 256, 0, stream>>>(W, sup, qry, WhiT, WloT, (short*)0,
                                     (short*)0, (short*)0);
    gemm_all_k<<<768, 256, 0, stream>>>(sup, qry, WhiT, WloT, b, emb);
    gramdiag_k<<<1280, 256, 0, stream>>>(emb, G);
    kmeans3_k<<<16, 64, 0, stream>>>(G, wts);
    proto_k<<<16, 256, 0, stream>>>(emb, wts, protos);
    dist_k<<<512, 256, 0, stream>>>(emb, protos, out);
  }
}

// Round 11
// 440.277 us; speedup vs baseline: 1.0421x; 1.0278x over previous
//
#include <hip/hip_runtime.h>
#include <cstdint>
#include <cstddef>

// ClusterProtoNetwork: heterogeneous-block launches to fill idle CU slots:
//  1) prep_sw: W split-transpose || sup->bf16 hi/lo
//  2) gemm_supq: sup GEMM (512 blk) || qry->bf16 convert (256 blk)
//  3) gemm_qry_gram: qry GEMM (512) || gram skip-diag (256) || f64 diag (1024)
//  4) kmeans3 (1 wave/class) -> proto1/proto2 -> dist
// All math bit-identical to round 10.  JAX threefry (partitionable) RNG.

typedef __attribute__((ext_vector_type(4))) float f32x4;
typedef __attribute__((ext_vector_type(8))) short s16x8;
typedef __attribute__((ext_vector_type(4))) short s16x4;
typedef __attribute__((ext_vector_type(8))) __bf16 bf16x8;

__device__ __forceinline__ unsigned short f2bf(float f) {
  unsigned u = __float_as_uint(f);
  return (unsigned short)((u + 0x7FFFu + ((u >> 16) & 1u)) >> 16);  // RTNE
}
__device__ __forceinline__ float bf2f(unsigned short h) {
  return __uint_as_float(((unsigned)h) << 16);
}

typedef const __attribute__((address_space(1))) void GV;
typedef __attribute__((address_space(3))) void LV;
__device__ __forceinline__ void gload_lds16(const void* g, void* l) {
  __builtin_amdgcn_global_load_lds((GV*)g, (LV*)l, 16, 0, 0);
}
__device__ __forceinline__ f32x4 mfma16(bf16x8 a, bf16x8 b, f32x4 c) {
  return __builtin_amdgcn_mfma_f32_16x16x32_bf16(a, b, c, 0, 0, 0);
}
__device__ __forceinline__ float wave_sum(float v) {
#pragma unroll
  for (int st = 1; st < 64; st <<= 1) v += __shfl_xor(v, st);
  return v;
}

// ---------------- Threefry-2x32 (JAX-exact, 20 rounds) ----------------
__device__ __forceinline__ void tf2x32(unsigned k0, unsigned k1, unsigned x0,
                                       unsigned x1, unsigned& y0, unsigned& y1) {
  unsigned ks0 = k0, ks1 = k1, ks2 = k0 ^ k1 ^ 0x1BD11BDAu;
  x0 += ks0; x1 += ks1;
  const int rA[4] = {13, 15, 26, 6};
  const int rB[4] = {17, 29, 16, 24};
#define ROTL(v, d) (((v) << (d)) | ((v) >> (32 - (d))))
#define RG(R)                                     \
  _Pragma("unroll") for (int i = 0; i < 4; i++) { \
    x0 += x1; x1 = ROTL(x1, R[i]); x1 ^= x0;      \
  }
  RG(rA); x0 += ks1; x1 += ks2 + 1u;
  RG(rB); x0 += ks2; x1 += ks0 + 2u;
  RG(rA); x0 += ks0; x1 += ks1 + 3u;
  RG(rB); x0 += ks1; x1 += ks2 + 4u;
  RG(rA); x0 += ks2; x1 += ks0 + 5u;
#undef RG
#undef ROTL
  y0 = x0; y1 = x1;
}

// ---- 1. prep_sw: W -> WhiT/WloT (transposed split) || sup -> Shi/Slo ------
__global__ __launch_bounds__(256) void prep_sw_k(
    const float* __restrict__ W, const float* __restrict__ sup,
    short* __restrict__ WhiT, short* __restrict__ WloT,
    short* __restrict__ Shi, short* __restrict__ Slo) {
  __shared__ float tile[64][65];
  int t = threadIdx.x;
  if (blockIdx.x < 1024) {  // prepw: 64 k-tiles x 16 n-tiles of 64x64
    int bk = blockIdx.x & 63, bn = blockIdx.x >> 6;
#pragma unroll
    for (int i = 0; i < 4; i++) {
      int row = i * 16 + (t >> 4);
      int col = (t & 15) * 4;
      f32x4 v =
          *(const f32x4*)(W + (size_t)(bk * 64 + row) * 1024 + bn * 64 + col);
      tile[row][col + 0] = v[0]; tile[row][col + 1] = v[1];
      tile[row][col + 2] = v[2]; tile[row][col + 3] = v[3];
    }
    __syncthreads();
#pragma unroll
    for (int i = 0; i < 4; i++) {
      int nrow = i * 16 + (t >> 4);
      int kcol = (t & 15) * 4;
      s16x4 hv, lv;
#pragma unroll
      for (int e = 0; e < 4; e++) {
        float v = tile[kcol + e][nrow];
        unsigned short h = f2bf(v);
        hv[e] = (short)h;
        lv[e] = (short)f2bf(v - bf2f(h));
      }
      size_t off = (size_t)(bn * 64 + nrow) * 4096 + bk * 64 + kcol;
      *(s16x4*)(WhiT + off) = hv;
      *(s16x4*)(WloT + off) = lv;
    }
  } else {  // sup convert: grid-stride over 2M 8-elem chunks
    const size_t sup_n8 = (size_t)4096 * 4096 / 8;
    size_t stride = (size_t)(gridDim.x - 1024) * 256;
    for (size_t gid = (size_t)(blockIdx.x - 1024) * 256 + t; gid < sup_n8;
         gid += stride) {
      const float* src = sup + gid * 8;
      f32x4 v0 = *(const f32x4*)src, v1 = *(const f32x4*)(src + 4);
      s16x8 h, l;
#pragma unroll
      for (int e = 0; e < 4; e++) {
        unsigned short hh = f2bf(v0[e]);
        h[e] = (short)hh; l[e] = (short)f2bf(v0[e] - bf2f(hh));
      }
#pragma unroll
      for (int e = 0; e < 4; e++) {
        unsigned short hh = f2bf(v1[e]);
        h[4 + e] = (short)hh; l[4 + e] = (short)f2bf(v1[e] - bf2f(hh));
      }
      *(s16x8*)(Shi + gid * 8) = h;
      *(s16x8*)(Slo + gid * 8) = l;
    }
  }
}

// ---- 2. gemm_supq: sup GEMM (512 blk, BM=64, 3-product) || qry convert ----
__global__ __launch_bounds__(256) void gemm_supq_k(
    const short* __restrict__ Shi, const short* __restrict__ Slo,
    const short* __restrict__ WhiT, const short* __restrict__ WloT,
    const float* __restrict__ bias, float* __restrict__ emb,
    const float* __restrict__ qry, short* __restrict__ Qhi) {
  __shared__ short lds[24576];  // 48 KiB (3 blk/CU)
  const int t = threadIdx.x;
  if (blockIdx.x < 512) {
    short* Ah = lds;              // [64][64]
    short* Al = lds + 4096;       // [64][64]
    short* Bh = lds + 8192;       // [128][64]
    short* Bl = lds + 16384;      // [128][64]
    const int bid = blockIdx.x;
    const int bm = bid & 63, bn = bid >> 6;  // siblings +64 -> same XCD
    const int lane = t & 63, w = t >> 6;
    const int wr = w >> 1, wc = w & 1;  // wave tile 32 x 64
    const int fr = lane & 15, kg = lane >> 4;
    const int ls = lane >> 3, lc = lane & 7;
    const short* Ag = Shi + (size_t)bm * 64 * 4096;
    const short* Alg = Slo + (size_t)bm * 64 * 4096;
    f32x4 acc[2][4] = {};

    for (int kt = 0; kt < 64; ++kt) {
      const int k0 = kt * 64;
      __syncthreads();
      const int cch = (lc ^ ls) * 8;
#pragma unroll
      for (int j = 0; j < 2; j++) {
        int rowl = w * 16 + j * 8 + ls;
        size_t aoff = (size_t)rowl * 4096 + k0 + cch;
        int ldst = (w * 16 + j * 8) * 64;
        gload_lds16(Ag + aoff, Ah + ldst);
        gload_lds16(Alg + aoff, Al + ldst);
      }
#pragma unroll
      for (int j = 0; j < 4; j++) {
        int rowl = w * 32 + j * 8 + ls;
        size_t boff = (size_t)(bn * 128 + rowl) * 4096 + k0 + cch;
        int ldst = (w * 32 + j * 8) * 64;
        gload_lds16(WhiT + boff, Bh + ldst);
        gload_lds16(WloT + boff, Bl + ldst);
      }
      __syncthreads();
#pragma unroll
      for (int ks = 0; ks < 2; ++ks) {
        const int cx = ((ks * 4 + kg) ^ (fr & 7)) * 8;
        bf16x8 ahf[2], alf[2], bhf[4], blf[4];
#pragma unroll
        for (int mi = 0; mi < 2; mi++) {
          int arow = wr * 32 + mi * 16 + fr;
          ahf[mi] =
              __builtin_bit_cast(bf16x8, *(const s16x8*)(Ah + arow * 64 + cx));
          alf[mi] =
              __builtin_bit_cast(bf16x8, *(const s16x8*)(Al + arow * 64 + cx));
        }
#pragma unroll
        for (int ni = 0; ni < 4; ni++) {
          int brow = wc * 64 + ni * 16 + fr;
          bhf[ni] =
              __builtin_bit_cast(bf16x8, *(const s16x8*)(Bh + brow * 64 + cx));
          blf[ni] =
              __builtin_bit_cast(bf16x8, *(const s16x8*)(Bl + brow * 64 + cx));
        }
#pragma unroll
        for (int mi = 0; mi < 2; mi++)
#pragma unroll
          for (int ni = 0; ni < 4; ni++) {
            acc[mi][ni] = mfma16(ahf[mi], bhf[ni], acc[mi][ni]);
            acc[mi][ni] = mfma16(ahf[mi], blf[ni], acc[mi][ni]);
            acc[mi][ni] = mfma16(alf[mi], bhf[ni], acc[mi][ni]);
          }
      }
    }
#pragma unroll
    for (int ni = 0; ni < 4; ni++) {
      int gc = bn * 128 + wc * 64 + ni * 16 + fr;
      float bv = bias[gc];
#pragma unroll
      for (int mi = 0; mi < 2; mi++) {
        int gr = bm * 64 + wr * 32 + mi * 16 + kg * 4;
#pragma unroll
        for (int r = 0; r < 4; r++)
          emb[(size_t)(gr + r) * 1024 + gc] = acc[mi][ni][r] + bv;
      }
    }
  } else {
    // qry convert: 256 blocks grid-stride over 4M 8-elem chunks (hidden
    // under the sup GEMM's compute — uses idle 3rd block slot + spare HBM BW)
    const size_t qry_n8 = (size_t)8192 * 4096 / 8;
    size_t stride = (size_t)(gridDim.x - 512) * 256;
    for (size_t gid = (size_t)(blockIdx.x - 512) * 256 + t; gid < qry_n8;
         gid += stride) {
      const float* src = qry + gid * 8;
      f32x4 v0 = *(const f32x4*)src, v1 = *(const f32x4*)(src + 4);
      s16x8 h;
#pragma unroll
      for (int e = 0; e < 4; e++) h[e] = (short)f2bf(v0[e]);
#pragma unroll
      for (int e = 0; e < 4; e++) h[4 + e] = (short)f2bf(v1[e]);
      *(s16x8*)(Qhi + gid * 8) = h;
    }
  }
}

// ---- 3. gemm_qry_gram: qry GEMM (512) || gram skip-diag (256) || diag -----
__global__ __launch_bounds__(256) void gemm_qry_gram_k(
    const short* __restrict__ Qhi, const short* __restrict__ WhiT,
    const float* __restrict__ bias, float* __restrict__ emb,
    float* __restrict__ G) {
  __shared__ __align__(16) char smem[32768];
  const int t = threadIdx.x;
  if (blockIdx.x < 512) {
    // ---- query GEMM: BM=128, 1-product ----
    short* Ah = (short*)smem;
    short* Bh = (short*)(smem + 16384);
    const int bid = blockIdx.x;
    const int bm = bid & 63, bn = bid >> 6;  // siblings +64 -> same XCD
    const int lane = t & 63, w = t >> 6;
    const int wr = w >> 1, wc = w & 1;
    const int fr = lane & 15, kg = lane >> 4;
    const int ls = lane >> 3, lc = lane & 7;
    const short* Ag = Qhi + (size_t)bm * 128 * 4096;
    f32x4 acc[4][4] = {};

    for (int kt = 0; kt < 64; ++kt) {
      const int k0 = kt * 64;
      __syncthreads();
      const int cch = (lc ^ ls) * 8;
#pragma unroll
      for (int j = 0; j < 4; j++) {
        int rowl = w * 32 + j * 8 + ls;
        size_t aoff = (size_t)rowl * 4096 + k0 + cch;
        size_t boff = (size_t)(bn * 128 + rowl) * 4096 + k0 + cch;
        int ldst = (w * 32 + j * 8) * 64;
        gload_lds16(Ag + aoff, Ah + ldst);
        gload_lds16(WhiT + boff, Bh + ldst);
      }
      __syncthreads();
#pragma unroll
      for (int ks = 0; ks < 2; ++ks) {
        const int cx = ((ks * 4 + kg) ^ (fr & 7)) * 8;
        bf16x8 ahf[4], bhf[4];
#pragma unroll
        for (int mi = 0; mi < 4; mi++) {
          int arow = wr * 64 + mi * 16 + fr;
          ahf[mi] =
              __builtin_bit_cast(bf16x8, *(const s16x8*)(Ah + arow * 64 + cx));
        }
#pragma unroll
        for (int ni = 0; ni < 4; ni++) {
          int brow = wc * 64 + ni * 16 + fr;
          bhf[ni] =
              __builtin_bit_cast(bf16x8, *(const s16x8*)(Bh + brow * 64 + cx));
        }
#pragma unroll
        for (int mi = 0; mi < 4; mi++)
#pragma unroll
          for (int ni = 0; ni < 4; ni++)
            acc[mi][ni] = mfma16(ahf[mi], bhf[ni], acc[mi][ni]);
      }
    }
#pragma unroll
    for (int ni = 0; ni < 4; ni++) {
      int gc = bn * 128 + wc * 64 + ni * 16 + fr;
      float bv = bias[gc];
#pragma unroll
      for (int mi = 0; mi < 4; mi++) {
        int gr = 4096 + bm * 128 + wr * 64 + mi * 16 + kg * 4;
#pragma unroll
        for (int r = 0; r < 4; r++)
          emb[(size_t)(gr + r) * 1024 + gc] = acc[mi][ni][r] + bv;
      }
    }
  } else if (blockIdx.x < 768) {
    // ---- gram (diagonal skipped; reads only support emb rows) ----
    int bb = blockIdx.x - 512;
    int c = bb >> 4, tl = bb & 15, ti = tl >> 2, tj = tl & 3;
    float (*As)[36] = (float(*)[36])smem;           // 9216 B
    float (*Bs)[68] = (float(*)[68])(smem + 9216);  // 8704 B
    int ty = t >> 4, tx = t & 15;
    const float* base = emb + (size_t)c * 256 * 1024;
    float acc[4][4] = {};
    for (int k0 = 0; k0 < 1024; k0 += 32) {
      __syncthreads();
      {
        int r = t >> 2, seg = t & 3;
        const float* pa = base + (size_t)(ti * 64 + r) * 1024 + k0 + seg * 8;
        f32x4 va0 = *(const f32x4*)pa, va1 = *(const f32x4*)(pa + 4);
        *(f32x4*)(&As[r][seg * 8]) = va0;
        *(f32x4*)(&As[r][seg * 8 + 4]) = va1;
        const float* pb = base + (size_t)(tj * 64 + r) * 1024 + k0 + seg * 8;
        f32x4 vb0 = *(const f32x4*)pb, vb1 = *(const f32x4*)(pb + 4);
#pragma unroll
        for (int e = 0; e < 4; e++) Bs[seg * 8 + e][r] = vb0[e];
#pragma unroll
        for (int e = 0; e < 4; e++) Bs[seg * 8 + 4 + e][r] = vb1[e];
      }
      __syncthreads();
#pragma unroll 4
      for (int kk = 0; kk < 32; kk++) {
        float a0 = As[ty * 4 + 0][kk], a1 = As[ty * 4 + 1][kk];
        float a2 = As[ty * 4 + 2][kk], a3 = As[ty * 4 + 3][kk];
        f32x4 bv = *(const f32x4*)(&Bs[kk][tx * 4]);
#pragma unroll
        for (int jdx = 0; jdx < 4; jdx++) {
          acc[0][jdx] = fmaf(a0, bv[jdx], acc[0][jdx]);
          acc[1][jdx] = fmaf(a1, bv[jdx], acc[1][jdx]);
          acc[2][jdx] = fmaf(a2, bv[jdx], acc[2][jdx]);
          acc[3][jdx] = fmaf(a3, bv[jdx], acc[3][jdx]);
        }
      }
    }
#pragma unroll
    for (int i = 0; i < 4; i++) {
      int gr = ti * 64 + ty * 4 + i;
#pragma unroll
      for (int j = 0; j < 4; j++) {
        int gcl = tj * 64 + tx * 4 + j;
        if (gr != gcl)  // diagonal owned by the diag blocks
          G[(size_t)c * 65536 + (size_t)gr * 256 + gcl] = acc[i][j];
      }
    }
  } else {
    // ---- f64-exact diagonal (reads only support emb rows) ----
    int r = (blockIdx.x - 768) * 4 + (t >> 6);  // support row 0..4095
    int lane = t & 63;
    const float* x = emb + (size_t)r * 1024;
    double acc = 0.0;
#pragma unroll
    for (int ch = 0; ch < 16; ch++) {
      float v = x[ch * 64 + lane];
      acc = fma((double)v, (double)v, acc);
    }
#pragma unroll
    for (int st = 1; st < 64; st <<= 1) acc += __shfl_xor(acc, st);
    if (lane == 0) {
      int c = r >> 8, i = r & 255;
      G[(size_t)c * 65536 + (size_t)i * 256 + i] = (float)acc;
    }
  }
}

// ---- 2'. fallback GEMM (in-loop convert; used when ws too small) ----------
__global__ __launch_bounds__(256) void gemm_all_k(
    const float* __restrict__ sup, const float* __restrict__ qry,
    const short* __restrict__ WhiT, const short* __restrict__ WloT,
    const float* __restrict__ bias, float* __restrict__ emb) {
  __shared__ short lds[4 * 128 * 64];
  short* Ah = lds;
  short* Al = lds + 8192;
  short* Bh = lds + 16384;
  short* Bl = lds + 24576;
  const int bid = blockIdx.x;
  const int bm = bid % 96, bn = bid / 96;
  const bool is_sup = bm < 32;
  const int t = threadIdx.x, lane = t & 63, w = t >> 6;
  const int wr = w >> 1, wc = w & 1;
  const int fr = lane & 15, kg = lane >> 4;
  const float* Abase = is_sup ? (sup + (size_t)bm * 128 * 4096)
                              : (qry + (size_t)(bm - 32) * 128 * 4096);
  f32x4 acc[4][4] = {};
  const int ls = lane >> 3, lc = lane & 7;

  for (int kt = 0; kt < 64; ++kt) {
    const int k0 = kt * 64;
    __syncthreads();
#pragma unroll
    for (int i = 0; i < 4; i++) {
      int row = i * 32 + w * 8 + ls;
      const float* src = Abase + (size_t)row * 4096 + k0 + lc * 8;
      f32x4 v0 = *(const f32x4*)src;
      f32x4 v1 = *(const f32x4*)(src + 4);
      s16x8 hs;
#pragma unroll
      for (int e = 0; e < 4; e++) hs[e] = (short)f2bf(v0[e]);
#pragma unroll
      for (int e = 0; e < 4; e++) hs[4 + e] = (short)f2bf(v1[e]);
      int chunk = lc ^ (row & 7);
      *(s16x8*)(Ah + row * 64 + chunk * 8) = hs;
      if (is_sup) {
        s16x8 lsv;
#pragma unroll
        for (int e = 0; e < 4; e++)
          lsv[e] = (short)f2bf(v0[e] - bf2f((unsigned short)hs[e]));
#pragma unroll
        for (int e = 0; e < 4; e++)
          lsv[4 + e] = (short)f2bf(v1[e] - bf2f((unsigned short)hs[4 + e]));
        *(s16x8*)(Al + row * 64 + chunk * 8) = lsv;
      }
    }
#pragma unroll
    for (int j = 0; j < 4; j++) {
      int rowl = w * 32 + j * 8 + ls;
      int cch = (lc ^ (ls & 7)) * 8;
      size_t goff = (size_t)(bn * 128 + rowl) * 4096 + k0 + cch;
      gload_lds16(WhiT + goff, Bh + (w * 32 + j * 8) * 64);
      if (is_sup) gload_lds16(WloT + goff, Bl + (w * 32 + j * 8) * 64);
    }
    __syncthreads();
#pragma unroll
    for (int ks = 0; ks < 2; ++ks) {
      const int cx = ((ks * 4 + kg) ^ (fr & 7)) * 8;
      bf16x8 ahf[4], bhf[4];
#pragma unroll
      for (int mi = 0; mi < 4; mi++) {
        int arow = wr * 64 + mi * 16 + fr;
        ahf[mi] = __builtin_bit_cast(bf16x8, *(const s16x8*)(Ah + arow * 64 + cx));
      }
#pragma unroll
      for (int ni = 0; ni < 4; ni++) {
        int brow = wc * 64 + ni * 16 + fr;
        bhf[ni] = __builtin_bit_cast(bf16x8, *(const s16x8*)(Bh + brow * 64 + cx));
      }
      if (is_sup) {
        bf16x8 alf[4], blf[4];
#pragma unroll
        for (int mi = 0; mi < 4; mi++) {
          int arow = wr * 64 + mi * 16 + fr;
          alf[mi] =
              __builtin_bit_cast(bf16x8, *(const s16x8*)(Al + arow * 64 + cx));
        }
#pragma unroll
        for (int ni = 0; ni < 4; ni++) {
          int brow = wc * 64 + ni * 16 + fr;
          blf[ni] =
              __builtin_bit_cast(bf16x8, *(const s16x8*)(Bl + brow * 64 + cx));
        }
#pragma unroll
        for (int mi = 0; mi < 4; mi++)
#pragma unroll
          for (int ni = 0; ni < 4; ni++) {
            acc[mi][ni] = mfma16(ahf[mi], bhf[ni], acc[mi][ni]);
            acc[mi][ni] = mfma16(ahf[mi], blf[ni], acc[mi][ni]);
            acc[mi][ni] = mfma16(alf[mi], bhf[ni], acc[mi][ni]);
          }
      } else {
#pragma unroll
        for (int mi = 0; mi < 4; mi++)
#pragma unroll
          for (int ni = 0; ni < 4; ni++)
            acc[mi][ni] = mfma16(ahf[mi], bhf[ni], acc[mi][ni]);
      }
    }
  }
#pragma unroll
  for (int ni = 0; ni < 4; ni++) {
    int gc = bn * 128 + wc * 64 + ni * 16 + fr;
    float bv = bias[gc];
#pragma unroll
    for (int mi = 0; mi < 4; mi++) {
      int gr = bm * 128 + wr * 64 + mi * 16 + kg * 4;
#pragma unroll
      for (int r = 0; r < 4; r++)
        emb[(size_t)(gr + r) * 1024 + gc] = acc[mi][ni][r] + bv;
    }
  }
}

// ---- 3'. fallback gram+diag (one launch) ----------------------------------
__global__ __launch_bounds__(256) void gramdiag_k(const float* __restrict__ emb,
                                                  float* __restrict__ G) {
  if (blockIdx.x < 256) {
    int c = blockIdx.x >> 4, tl = blockIdx.x & 15, ti = tl >> 2, tj = tl & 3;
    __shared__ float As[64][36];
    __shared__ float Bs[32][68];
    int t = threadIdx.x, ty = t >> 4, tx = t & 15;
    const float* base = emb + (size_t)c * 256 * 1024;
    float acc[4][4] = {};
    for (int k0 = 0; k0 < 1024; k0 += 32) {
      __syncthreads();
      {
        int r = t >> 2, seg = t & 3;
        const float* pa = base + (size_t)(ti * 64 + r) * 1024 + k0 + seg * 8;
        f32x4 va0 = *(const f32x4*)pa, va1 = *(const f32x4*)(pa + 4);
        *(f32x4*)(&As[r][seg * 8]) = va0;
        *(f32x4*)(&As[r][seg * 8 + 4]) = va1;
        const float* pb = base + (size_t)(tj * 64 + r) * 1024 + k0 + seg * 8;
        f32x4 vb0 = *(const f32x4*)pb, vb1 = *(const f32x4*)(pb + 4);
#pragma unroll
        for (int e = 0; e < 4; e++) Bs[seg * 8 + e][r] = vb0[e];
#pragma unroll
        for (int e = 0; e < 4; e++) Bs[seg * 8 + 4 + e][r] = vb1[e];
      }
      __syncthreads();
#pragma unroll 4
      for (int kk = 0; kk < 32; kk++) {
        float a0 = As[ty * 4 + 0][kk], a1 = As[ty * 4 + 1][kk];
        float a2 = As[ty * 4 + 2][kk], a3 = As[ty * 4 + 3][kk];
        f32x4 bv = *(const f32x4*)(&Bs[kk][tx * 4]);
#pragma unroll
        for (int jdx = 0; jdx < 4; jdx++) {
          acc[0][jdx] = fmaf(a0, bv[jdx], acc[0][jdx]);
          acc[1][jdx] = fmaf(a1, bv[jdx], acc[1][jdx]);
          acc[2][jdx] = fmaf(a2, bv[jdx], acc[2][jdx]);
          acc[3][jdx] = fmaf(a3, bv[jdx], acc[3][jdx]);
        }
      }
    }
#pragma unroll
    for (int i = 0; i < 4; i++) {
      int gr = ti * 64 + ty * 4 + i;
#pragma unroll
      for (int j = 0; j < 4; j++) {
        int gcl = tj * 64 + tx * 4 + j;
        if (gr != gcl)
          G[(size_t)c * 65536 + (size_t)gr * 256 + gcl] = acc[i][j];
      }
    }
  } else {
    int r = (blockIdx.x - 256) * 4 + (threadIdx.x >> 6);
    int lane = threadIdx.x & 63;
    const float* x = emb + (size_t)r * 1024;
    double acc = 0.0;
#pragma unroll
    for (int ch = 0; ch < 16; ch++) {
      float v = x[ch * 64 + lane];
      acc = fma((double)v, (double)v, acc);
    }
#pragma unroll
    for (int st = 1; st < 64; st <<= 1) acc += __shfl_xor(acc, st);
    if (lane == 0) {
      int c = r >> 8, i = r & 255;
      G[(size_t)c * 65536 + (size_t)i * 256 + i] = (float)acc;
    }
  }
}

// ---- 4. one-wave-per-class kmeans: 64 threads, 4 points/lane, 0 barriers --
#define APPLY1(db, nb, gg, p)                        \
  if ((db) & 1u)  s[p][0] += ((nb) & 1u)  ? (gg) : -(gg); \
  if ((db) & 2u)  s[p][1] += ((nb) & 2u)  ? (gg) : -(gg); \
  if ((db) & 4u)  s[p][2] += ((nb) & 4u)  ? (gg) : -(gg); \
  if ((db) & 8u)  s[p][3] += ((nb) & 8u)  ? (gg) : -(gg); \
  if ((db) & 16u) s[p][4] += ((nb) & 16u) ? (gg) : -(gg);

__global__ __launch_bounds__(64) void kmeans3_k(const float* __restrict__ G,
                                                float* __restrict__ wts) {
  const int c = blockIdx.x;
  const int lane = threadIdx.x;  // one wave per class
  unsigned o0, o1, s0k, s1k;
  tf2x32(0u, 42u, 0u, (unsigned)c, o0, o1);
  tf2x32(o0, o1, 0u, 1u, s0k, s1k);
  unsigned long long key[4];
#pragma unroll
  for (int q = 0; q < 4; q++) {
    unsigned y0, y1;
    tf2x32(s0k, s1k, 0u, (unsigned)(lane + 64 * q), y0, y1);
    key[q] = ((unsigned long long)(y0 ^ y1) << 32) | (unsigned)(lane + 64 * q);
  }
  int idx5[5];
#pragma unroll
  for (int r = 0; r < 5; r++) {
    unsigned long long mn = key[0];
#pragma unroll
    for (int q = 1; q < 4; q++) mn = key[q] < mn ? key[q] : mn;
#pragma unroll
    for (int st = 1; st < 64; st <<= 1) {
      unsigned long long o = __shfl_xor(mn, st);
      mn = o < mn ? o : mn;
    }
    int widx = (int)(unsigned)(mn & 0xffffffffu);
    idx5[r] = widx;
#pragma unroll
    for (int q = 0; q < 4; q++)
      if (widx == lane + 64 * q) key[q] = ~0ull;
  }
  unsigned m[4];
#pragma unroll
  for (int q = 0; q < 4; q++) {
    unsigned mm = 0;
#pragma unroll
    for (int k = 0; k < 5; k++)
      if (idx5[k] == lane + 64 * q) mm |= 1u << k;
    m[q] = mm;
  }
  const float* Gc = G + (size_t)c * 65536;
  float s[4][5];
#pragma unroll
  for (int k = 0; k < 5; k++) {
    const float* row = Gc + (size_t)idx5[k] * 256;
#pragma unroll
    for (int q = 0; q < 4; q++) s[q][k] = row[lane + 64 * q];
  }
  float Minv[5] = {1.0f, 1.0f, 1.0f, 1.0f, 1.0f};

  for (int it = 0; it < 100; ++it) {
    float Tu[5], C2[5];
#pragma unroll
    for (int k = 0; k < 5; k++) {
      float v = 0.0f;
#pragma unroll
      for (int q = 0; q < 4; q++)
        v += ((m[q] >> k) & 1u) ? s[q][k] : 0.0f;
#pragma unroll
      for (int st = 1; st < 64; st <<= 1) v += __shfl_xor(v, st);
      float iv = Minv[k];
      Tu[k] = v * iv * iv;
      C2[k] = -2.0f * iv;
    }
    int a[4];
#pragma unroll
    for (int q = 0; q < 4; q++) {
      float d0 = fmaf(C2[0], s[q][0], Tu[0]);
      float d1 = fmaf(C2[1], s[q][1], Tu[1]);
      float d2 = fmaf(C2[2], s[q][2], Tu[2]);
      float d3 = fmaf(C2[3], s[q][3], Tu[3]);
      float d4 = fmaf(C2[4], s[q][4], Tu[4]);
      int at = 0;
      float dmn = d0;
      if (d1 < dmn) { dmn = d1; at = 1; }
      if (d2 < dmn) { dmn = d2; at = 2; }
      if (d3 < dmn) { dmn = d3; at = 3; }
      if (d4 < dmn) { dmn = d4; at = 4; }
      a[q] = at;
    }
    int cnt[5];
#pragma unroll
    for (int k = 0; k < 5; k++) {
      int v = (a[0] == k) + (a[1] == k) + (a[2] == k) + (a[3] == k);
#pragma unroll
      for (int st = 1; st < 64; st <<= 1) v += __shfl_xor(v, st);
      cnt[k] = v;
    }
    unsigned nm[4], dm[4];
#pragma unroll
    for (int q = 0; q < 4; q++) {
      unsigned nv = 0;
#pragma unroll
      for (int k = 0; k < 5; k++) {
        int bit = (cnt[k] > 0) ? (a[q] == k ? 1 : 0) : (int)((m[q] >> k) & 1u);
        nv |= ((unsigned)bit) << k;
      }
      nm[q] = nv;
      dm[q] = nv ^ m[q];
    }
    unsigned long long bal[4];
#pragma unroll
    for (int q = 0; q < 4; q++) bal[q] = __ballot(dm[q] != 0);
    if ((bal[0] | bal[1] | bal[2] | bal[3]) == 0) break;  // fixed point
#pragma unroll
    for (int q = 0; q < 4; q++) m[q] = nm[q];
#pragma unroll
    for (int k = 0; k < 5; k++)
      if (cnt[k] > 0) Minv[k] = 1.0f / (float)cnt[k];
#pragma unroll
    for (int q = 0; q < 4; q++) {
      unsigned long long mask = bal[q];
      while (mask) {
#define GATHER(i)                                                      \
        int j##i = -1;                                                 \
        unsigned d##i = 0, e##i = 0;                                   \
        float g##i##0 = 0, g##i##1 = 0, g##i##2 = 0, g##i##3 = 0;      \
        if (mask) {                                                    \
          j##i = __builtin_ctzll(mask);                                \
          mask &= mask - 1;                                            \
          d##i = __shfl(dm[q], j##i);                                  \
          e##i = __shfl(nm[q], j##i);                                  \
          const float* row = Gc + (size_t)(q * 64 + j##i) * 256 + lane;\
          g##i##0 = row[0];  g##i##1 = row[64];                        \
          g##i##2 = row[128]; g##i##3 = row[192];                      \
        }
        GATHER(0) GATHER(1) GATHER(2) GATHER(3)
        GATHER(4) GATHER(5) GATHER(6) GATHER(7)
#undef GATHER
#define DOAPPLY(i)                        \
        if (j##i >= 0) {                  \
          APPLY1(d##i, e##i, g##i##0, 0)  \
          APPLY1(d##i, e##i, g##i##1, 1)  \
          APPLY1(d##i, e##i, g##i##2, 2)  \
          APPLY1(d##i, e##i, g##i##3, 3)  \
        }
        DOAPPLY(0) DOAPPLY(1) DOAPPLY(2) DOAPPLY(3)
        DOAPPLY(4) DOAPPLY(5) DOAPPLY(6) DOAPPLY(7)
#undef DOAPPLY
      }
    }
  }
#pragma unroll
  for (int q = 0; q < 4; q++) {
    float wv = 0.0f;
#pragma unroll
    for (int k = 0; k < 5; k++)
      if ((m[q] >> k) & 1u) wv += 0.2f * Minv[k];
    wts[c * 256 + lane + 64 * q] = wv;
  }
}

// ---- 6a. proto partials: 256 blocks (c, 16-row segment) -------------------
__global__ __launch_bounds__(256) void proto1_k(const float* __restrict__ emb,
                                                const float* __restrict__ wts,
                                                float* __restrict__ part) {
  int c = blockIdx.x & 15, seg = blockIdx.x >> 4, t = threadIdx.x;
  __shared__ float wl[16];
  if (t < 16) wl[t] = wts[c * 256 + seg * 16 + t];
  __syncthreads();
  f32x4 acc = {};
  const float* base = emb + (size_t)(c * 256 + seg * 16) * 1024 + t * 4;
#pragma unroll
  for (int j = 0; j < 16; j++) {
    f32x4 v = *(const f32x4*)(base + (size_t)j * 1024);
    float wj = wl[j];
#pragma unroll
    for (int e = 0; e < 4; e++) acc[e] = fmaf(wj, v[e], acc[e]);
  }
  *(f32x4*)(part + ((size_t)seg * 16 + c) * 1024 + t * 4) = acc;
}

// ---- 6b. proto reduce: fixed ascending-seg order (deterministic) ----------
__global__ __launch_bounds__(256) void proto2_k(const float* __restrict__ part,
                                                float* __restrict__ protos) {
  int c = blockIdx.x, t = threadIdx.x;
  f32x4 acc = {};
#pragma unroll
  for (int seg = 0; seg < 16; seg++) {
    f32x4 v = *(const f32x4*)(part + ((size_t)seg * 16 + c) * 1024 + t * 4);
#pragma unroll
    for (int e = 0; e < 4; e++) acc[e] += v[e];
  }
  *(f32x4*)(protos + (size_t)c * 1024 + t * 4) = acc;
}

// ---- 6'. fallback single-kernel proto ------------------------------------
__global__ __launch_bounds__(256) void proto_k(const float* __restrict__ emb,
                                               const float* __restrict__ wts,
                                               float* __restrict__ protos) {
  int c = blockIdx.x, t = threadIdx.x;
  __shared__ float wl[256];
  wl[t] = wts[c * 256 + t];
  __syncthreads();
  f32x4 acc = {};
  const float* base = emb + (size_t)c * 256 * 1024 + t * 4;
  for (int j = 0; j < 256; j++) {
    f32x4 v = *(const f32x4*)(base + (size_t)j * 1024);
    float wj = wl[j];
#pragma unroll
    for (int e = 0; e < 4; e++) acc[e] = fmaf(wj, v[e], acc[e]);
  }
  *(f32x4*)(protos + (size_t)c * 1024 + t * 4) = acc;
}

// ---------------- 7. output: -cdist(query_emb, protos) ---------------------
__global__ __launch_bounds__(256) void dist_k(const float* __restrict__ emb,
                                              const float* __restrict__ protos,
                                              float* __restrict__ out) {
  __shared__ float P[16 * 1024];  // 64 KiB
  int t = threadIdx.x, lane = t & 63, w = t >> 6;
#pragma unroll
  for (int i = 0; i < 16; i++) {
    int off = i * 1024 + t * 4;
    *(f32x4*)(P + off) = *(const f32x4*)(protos + off);
  }
  __syncthreads();
  float psq_keep = 0.0f;
  for (int p = 0; p < 16; p++) {
    float partial = 0.0f;
#pragma unroll
    for (int ch = 0; ch < 16; ch++) {
      float x = P[p * 1024 + ch * 64 + lane];
      partial = fmaf(x, x, partial);
    }
    partial = wave_sum(partial);
    if (lane == p) psq_keep = partial;
  }
  const float* qbase = emb + (size_t)4096 * 1024;
  int r0 = blockIdx.x * 16 + w * 4;
  for (int ri = 0; ri < 4; ri++) {
    int row = r0 + ri;
    const float* q = qbase + (size_t)row * 1024;
    float qv[16];
#pragma unroll
    for (int ch = 0; ch < 16; ch++) qv[ch] = q[ch * 64 + lane];
    float qsq = 0.0f;
#pragma unroll
    for (int ch = 0; ch < 16; ch++) qsq = fmaf(qv[ch], qv[ch], qsq);
    qsq = wave_sum(qsq);
    float dsel = 0.0f;
    for (int p = 0; p < 16; p++) {
      float dp = 0.0f;
#pragma unroll
      for (int ch = 0; ch < 16; ch++)
        dp = fmaf(qv[ch], P[p * 1024 + ch * 64 + lane], dp);
      dp = wave_sum(dp);
      if (lane == p) dsel = dp;
    }
    if (lane < 16) {
      float d2 = qsq - 2.0f * dsel + psq_keep;
      d2 = fmaxf(d2, 0.0f);
      out[(size_t)row * 16 + lane] = -sqrtf(d2);
    }
  }
}

// ---------------- launch ---------------------------------------------------
extern "C" void kernel_launch(void* const* d_in, const int* in_sizes, int n_in,
                              void* d_out, int out_size, void* d_ws,
                              size_t ws_size, hipStream_t stream) {
  const float* sup = (const float*)d_in[0];
  const float* qry = (const float*)d_in[1];
  const float* W = (const float*)d_in[2];
  const float* b = (const float*)d_in[3];
  float* out = (float*)d_out;
  char* ws = (char*)d_ws;
  (void)in_sizes; (void)n_in; (void)out_size;

  const size_t NEED_FAST = 206651392ULL;  // ~197 MiB
  if (ws_size >= NEED_FAST) {
    short* WhiT = (short*)(ws + 0);            //  8 MiB
    short* WloT = (short*)(ws + 8388608);      //  8 MiB
    short* Shi = (short*)(ws + 16777216);      // 32 MiB
    short* Slo = (short*)(ws + 50331648);      // 32 MiB
    short* Qhi = (short*)(ws + 83886080);      // 64 MiB
    float* emb = (float*)(ws + 150994944);     // 48 MiB
    float* G = (float*)(ws + 201326592);       //  4 MiB
    float* wts = (float*)(ws + 205520896);     // 16 KiB
    float* protos = (float*)(ws + 205537280);  // 64 KiB
    float* part = (float*)(ws + 205602816);    //  1 MiB

    prep_sw_k<<<2048, 256, 0, stream>>>(W, sup, WhiT, WloT, Shi, Slo);
    gemm_supq_k<<<768, 256, 0, stream>>>(Shi, Slo, WhiT, WloT, b, emb, qry,
                                         Qhi);
    gemm_qry_gram_k<<<1792, 256, 0, stream>>>(Qhi, WhiT, b, emb, G);
    kmeans3_k<<<16, 64, 0, stream>>>(G, wts);
    proto1_k<<<256, 256, 0, stream>>>(emb, wts, part);
    proto2_k<<<16, 256, 0, stream>>>(part, protos);
    dist_k<<<512, 256, 0, stream>>>(emb, protos, out);
  } else {
    short* WhiT = (short*)(ws + 0);
    short* WloT = (short*)(ws + 8388608);
    float* emb = (float*)(ws + 16777216);
    float* G = (float*)(ws + 67108864);
    float* wts = (float*)(ws + 71303168);
    float* protos = (float*)(ws + 71319552);

    prep_sw_k<<<1024, 256, 0, stream>>>(W, sup, WhiT, WloT, (short*)0,
                                        (short*)0);
    gemm_all_k<<<768, 256, 0, stream>>>(sup, qry, WhiT, WloT, b, emb);
    gramdiag_k<<<1280, 256, 0, stream>>>(emb, G);
    kmeans3_k<<<16, 64, 0, stream>>>(G, wts);
    proto_k<<<16, 256, 0, stream>>>(emb, wts, protos);
    dist_k<<<512, 256, 0, stream>>>(emb, protos, out);
  }
}